// Round 12
// baseline (268.381 us; speedup 1.0000x reference)
//
#include <hip/hip_runtime.h>

#define NB 64
#define NN 1024
#define WDIM 64
#define RR 4
#define HID 512
#define XID 471
#define EPSF 1e-6f

// ---- d_out offsets (floats) ----
#define O_OUT   0
#define O_XI    16384
#define O_RW    46528
#define O_MEM   308672
#define O_USAGE 4502976

// ---- ws offsets (floats) ----
#define WS_RFPART   0          // [4][64][256] read_flat partials
#define WS_H        65536      // [64][512]
#define WS_IFACE    98304      // [64][480]
#define WS_ALLOC    129024     // [64][1024]
#define WS_WW       194560     // [64][1024]
#define WS_DIAG     784896     // [64][1024]
#define WS_ROWAB    850432     // [64][1024][8]
#define WS_COLPART  1899008    // [16][64][1024][8] col partials (33.5 MB)
#define WS_EW       10287616   // [4][64]
#define WS_SIMWE    10287872   // [64][1024]
#define WS_ERP      10353408   // [4][64][4]
#define WS_ER       10354432   // [64][1024][4]
#define WS_STP      10616576   // [4][64][8]
#define WS_V2       10620928   // [64][1024][4] u32 bf16-packed {rw, ww*rw}

// ---- iface per-b layout (stride 480) ----
#define IF_KN     0
#define IF_WKN    256
#define IF_ERASE  320
#define IF_WVEC   384
#define IF_RSTR   448
#define IF_FREE   452
#define IF_WSTR   456
#define IF_AG     457
#define IF_WG     458
#define IF_MODES  460
#define IF_STRIDE 480

__device__ __forceinline__ float sigmoidf_(float x) { return 1.0f / (1.0f + expf(-x)); }
__device__ __forceinline__ float oneplusf_(float x) {
  return 1.0f + ((x > 20.0f) ? x : log1pf(expf(x)));
}
__device__ __forceinline__ float blo(unsigned u) { return __uint_as_float(u << 16); }
__device__ __forceinline__ float bhi(unsigned u) { return __uint_as_float(u & 0xFFFF0000u); }
__device__ __forceinline__ unsigned packbf(float a, float b) {
  return ((__float_as_uint(a) + 0x8000u) >> 16) |
         ((__float_as_uint(b) + 0x8000u) & 0xFFFF0000u);
}

typedef const __attribute__((address_space(1))) void gas_void;
typedef __attribute__((address_space(3))) void las_void;
__device__ __forceinline__ void gl16(const float* g, float* l) {
  __builtin_amdgcn_global_load_lds((gas_void*)g, (las_void*)l, 16, 0, 0);
}

// 1) read_flat partials
__global__ __launch_bounds__(1024) void k_read_flat(const float* __restrict__ mem,
                                                    const float* __restrict__ rw,
                                                    float* __restrict__ ws) {
  __shared__ float red[1024];
  const int q = blockIdx.x, b = blockIdx.y, t = threadIdx.x;
  const int rwi = t & 255;
  const int r = rwi >> 6, w = rwi & 63;
  const int ng = t >> 8;
  const int n0 = (q << 8) + (ng << 6);
  const float* M  = mem + ((size_t)(b << 10) + n0) * WDIM;
  const float* Rw = rw  + ((size_t)(b << 10) + n0) * RR;
  float a0 = 0.f, a1 = 0.f, a2 = 0.f, a3 = 0.f;
  for (int n = 0; n < 64; n += 4) {
    a0 += M[(n + 0) * WDIM + w] * Rw[(n + 0) * RR + r];
    a1 += M[(n + 1) * WDIM + w] * Rw[(n + 1) * RR + r];
    a2 += M[(n + 2) * WDIM + w] * Rw[(n + 2) * RR + r];
    a3 += M[(n + 3) * WDIM + w] * Rw[(n + 3) * RR + r];
  }
  red[t] = (a0 + a1) + (a2 + a3);
  __syncthreads();
  if (t < 256)
    ws[WS_RFPART + (((q << 6) + b) << 8) + t] =
        red[t] + red[t + 256] + red[t + 512] + red[t + 768];
}

// 2) h = relu([x, read_flat] @ W1 + b1), col-split grid (2,64); 4-acc ILP
__global__ __launch_bounds__(256) void k_h(const float* __restrict__ x,
                                           const float* __restrict__ W1,
                                           const float* __restrict__ b1,
                                           float* __restrict__ ws) {
  __shared__ float cat[768];
  const int ch = blockIdx.x, b = blockIdx.y, t = threadIdx.x;
  cat[t] = x[b * 512 + t];
  cat[256 + t] = x[b * 512 + 256 + t];
  {
    float s = 0.0f;
    #pragma unroll
    for (int q = 0; q < 4; ++q) s += ws[WS_RFPART + (((q << 6) + b) << 8) + t];
    cat[512 + t] = s;
  }
  __syncthreads();
  const int col = (ch << 8) + t;
  float a0 = 0.f, a1 = 0.f, a2 = 0.f, a3 = 0.f;
  #pragma unroll 4
  for (int k = 0; k < 768; k += 4) {
    a0 = fmaf(cat[k + 0], W1[(k + 0) * 512 + col], a0);
    a1 = fmaf(cat[k + 1], W1[(k + 1) * 512 + col], a1);
    a2 = fmaf(cat[k + 2], W1[(k + 2) * 512 + col], a2);
    a3 = fmaf(cat[k + 3], W1[(k + 3) * 512 + col], a3);
  }
  ws[WS_H + b * 512 + col] = fmaxf(b1[col] + (a0 + a1) + (a2 + a3), 0.0f);
}

// 3) xi (blocks 0,1) and output (block 2), grid (3,64); 4-acc ILP
__global__ __launch_bounds__(256) void k_xiout(const float* __restrict__ Wxi,
                                               const float* __restrict__ bxi,
                                               const float* __restrict__ Wo,
                                               const float* __restrict__ bo,
                                               const float* __restrict__ Wr,
                                               const float* __restrict__ br,
                                               const float* __restrict__ ws,
                                               float* __restrict__ out) {
  __shared__ float h[512];
  __shared__ float rf[256];
  const int m = blockIdx.x, b = blockIdx.y, t = threadIdx.x;
  h[t] = ws[WS_H + b * 512 + t];
  h[256 + t] = ws[WS_H + b * 512 + 256 + t];
  if (m == 2) {
    float s = 0.0f;
    #pragma unroll
    for (int q = 0; q < 4; ++q) s += ws[WS_RFPART + (((q << 6) + b) << 8) + t];
    rf[t] = s;
  }
  __syncthreads();
  if (m < 2) {
    const int col = (m << 8) + t;
    if (col < XID) {
      float a0 = 0.f, a1 = 0.f, a2 = 0.f, a3 = 0.f;
      #pragma unroll 4
      for (int j = 0; j < 512; j += 4) {
        a0 = fmaf(h[j + 0], Wxi[(j + 0) * XID + col], a0);
        a1 = fmaf(h[j + 1], Wxi[(j + 1) * XID + col], a1);
        a2 = fmaf(h[j + 2], Wxi[(j + 2) * XID + col], a2);
        a3 = fmaf(h[j + 3], Wxi[(j + 3) * XID + col], a3);
      }
      out[O_XI + b * XID + col] = bxi[col] + (a0 + a1) + (a2 + a3);
    }
  } else {
    float a0 = 0.f, a1 = 0.f, a2 = 0.f, a3 = 0.f;
    #pragma unroll 4
    for (int j = 0; j < 512; j += 4) {
      a0 = fmaf(h[j + 0], Wo[(j + 0) * 256 + t], a0);
      a1 = fmaf(h[j + 1], Wo[(j + 1) * 256 + t], a1);
      a2 = fmaf(h[j + 2], Wo[(j + 2) * 256 + t], a2);
      a3 = fmaf(h[j + 3], Wo[(j + 3) * 256 + t], a3);
    }
    #pragma unroll 4
    for (int j = 0; j < 256; j += 4) {
      a0 = fmaf(rf[j + 0], Wr[(j + 0) * 256 + t], a0);
      a1 = fmaf(rf[j + 1], Wr[(j + 1) * 256 + t], a1);
      a2 = fmaf(rf[j + 2], Wr[(j + 2) * 256 + t], a2);
      a3 = fmaf(rf[j + 3], Wr[(j + 3) * 256 + t], a3);
    }
    out[O_OUT + b * 256 + t] = bo[t] + br[t] + (a0 + a1) + (a2 + a3);
  }
}

// 4) interface activations (one wave per b)
__global__ __launch_bounds__(64) void k_iface(const float* __restrict__ out,
                                              float* __restrict__ ws) {
  const int b = blockIdx.x, w = threadIdx.x;
  const float* xi = out + O_XI + b * XID;
  float* f = ws + WS_IFACE + (size_t)b * IF_STRIDE;
  #pragma unroll
  for (int r = 0; r < 4; ++r) {
    float kv = xi[r * 64 + w];
    float ss = kv * kv;
    #pragma unroll
    for (int s = 32; s; s >>= 1) ss += __shfl_xor(ss, s);
    f[IF_KN + r * 64 + w] = kv * rsqrtf(ss + EPSF);
  }
  {
    float kv = xi[260 + w];
    float ss = kv * kv;
    #pragma unroll
    for (int s = 32; s; s >>= 1) ss += __shfl_xor(ss, s);
    f[IF_WKN + w] = kv * rsqrtf(ss + EPSF);
  }
  f[IF_ERASE + w] = sigmoidf_(xi[325 + w]);
  f[IF_WVEC + w] = xi[389 + w];
  if (w < 4) {
    f[IF_RSTR + w] = oneplusf_(xi[256 + w]);
    f[IF_FREE + w] = sigmoidf_(xi[453 + w]);
    float a = xi[459 + w * 3], bb = xi[459 + w * 3 + 1], c = xi[459 + w * 3 + 2];
    float m = fmaxf(a, fmaxf(bb, c));
    float ea = expf(a - m), eb = expf(bb - m), ec = expf(c - m);
    float s = ea + eb + ec;
    f[IF_MODES + w * 3] = ea / s;
    f[IF_MODES + w * 3 + 1] = eb / s;
    f[IF_MODES + w * 3 + 2] = ec / s;
  }
  if (w == 0) {
    f[IF_WSTR] = oneplusf_(xi[324]);
    f[IF_AG] = sigmoidf_(xi[457]);
    f[IF_WG] = sigmoidf_(xi[458]);
  }
}

// 5) fused: blocks 0-3 usage_new+allocation; blocks 4-7 write-content exp+diag
__global__ __launch_bounds__(256) void k_allocwc(const float* __restrict__ rw,
                                                 const float* __restrict__ usage,
                                                 const float* __restrict__ wwp,
                                                 const float* __restrict__ mem,
                                                 const float* __restrict__ link,
                                                 float* __restrict__ ws,
                                                 float* __restrict__ ousage) {
  __shared__ float2 ul[1024];
  __shared__ float wkn[64];
  __shared__ float red[4];
  const int z = blockIdx.x, b = blockIdx.y, t = threadIdx.x;
  const float* f = ws + WS_IFACE + (size_t)b * IF_STRIDE;
  if (z < 4) {
    const int q = z;
    const float f0 = f[IF_FREE + 0], f1 = f[IF_FREE + 1];
    const float f2 = f[IF_FREE + 2], f3 = f[IF_FREE + 3];
    #pragma unroll
    for (int c = 0; c < 4; ++c) {
      const int n = (c << 8) + t;
      const int i = (b << 10) + n;
      const float4 r4 = *(const float4*)(rw + (size_t)i * 4);
      float ret = (1.0f - f0 * r4.x) * (1.0f - f1 * r4.y) *
                  (1.0f - f2 * r4.z) * (1.0f - f3 * r4.w);
      float u = usage[i], w = wwp[i];
      float un = (u + w - u * w) * ret;
      if (c == q) ousage[i] = un;
      ul[n] = make_float2(un, logf(un));
    }
    __syncthreads();
    const int i = (q << 8) + t;
    const float ui = ul[i].x;
    float s0 = 0.f, s1 = 0.f, s2 = 0.f, s3 = 0.f;
    #pragma unroll 2
    for (int j = 0; j < 1024; j += 4) {
      float2 v0 = ul[j], v1 = ul[j + 1], v2 = ul[j + 2], v3 = ul[j + 3];
      s0 += ((v0.x < ui) || (v0.x == ui && j + 0 < i)) ? v0.y : 0.0f;
      s1 += ((v1.x < ui) || (v1.x == ui && j + 1 < i)) ? v1.y : 0.0f;
      s2 += ((v2.x < ui) || (v2.x == ui && j + 2 < i)) ? v2.y : 0.0f;
      s3 += ((v3.x < ui) || (v3.x == ui && j + 3 < i)) ? v3.y : 0.0f;
    }
    ws[WS_ALLOC + (b << 10) + i] = (1.0f - ui) * expf((s0 + s1) + (s2 + s3));
  } else {
    const int q = z - 4;
    const int wv = t >> 6, lane = t & 63;
    if (t < 64) wkn[t] = f[IF_WKN + t];
    __syncthreads();
    const int n = (q << 8) + t;
    const size_t bn = (size_t)(b << 10) + n;
    const float* Mrow = mem + bn * WDIM;
    float dot = 0.0f, ssq = 0.0f;
    #pragma unroll
    for (int w = 0; w < 64; w += 4) {
      float4 m4 = *(const float4*)(Mrow + w);
      float4 k4 = *(const float4*)(&wkn[w]);
      dot += m4.x * k4.x + m4.y * k4.y + m4.z * k4.z + m4.w * k4.w;
      ssq += m4.x * m4.x + m4.y * m4.y + m4.z * m4.z + m4.w * m4.w;
    }
    float e = expf(dot * rsqrtf(ssq + EPSF) * f[IF_WSTR]);
    ws[WS_SIMWE + bn] = e;
    ws[WS_DIAG + bn] = link[bn * 1024 + n];
    float se = e;
    #pragma unroll
    for (int s = 32; s; s >>= 1) se += __shfl_xor(se, s);
    if (lane == 0) red[wv] = se;
    __syncthreads();
    if (t == 0) ws[WS_EW + (q << 6) + b] = red[0] + red[1] + red[2] + red[3];
  }
}

// 6) ww + packed V2 + ST partials + memory_new + fused read-content exp
__global__ __launch_bounds__(256) void k_wcww_b(const float* __restrict__ mem,
                                                const float* __restrict__ rw,
                                                const float* __restrict__ prec,
                                                float* __restrict__ ws,
                                                float* __restrict__ omem) {
  __shared__ float kn[256];
  __shared__ float shev[128];
  __shared__ float red8[4][8];
  __shared__ float red4[4][4];
  const int q = blockIdx.x, b = blockIdx.y, t = threadIdx.x;
  const int wv = t >> 6, lane = t & 63;
  const float* f = ws + WS_IFACE + (size_t)b * IF_STRIDE;
  kn[t] = f[IF_KN + t];
  if (t < 64) shev[t] = f[IF_ERASE + t];
  else if (t < 128) shev[t] = f[IF_WVEC + (t - 64)];
  __syncthreads();
  const float denom = ws[WS_EW + b] + ws[WS_EW + 64 + b] +
                      ws[WS_EW + 128 + b] + ws[WS_EW + 192 + b];
  const int n = (q << 8) + t;
  const size_t bn = (size_t)(b << 10) + n;
  float wc = ws[WS_SIMWE + bn] / denom;
  float ag = f[IF_AG], wg = f[IF_WG];
  float ww = wg * (ag * ws[WS_ALLOC + bn] + (1.0f - ag) * wc);
  ws[WS_WW + bn] = ww;
  float4 r4 = *(const float4*)(rw + bn * 4);
  // packed bf16 {rw[0..3], ww*rw[0..3]} -> one uint4 per n
  {
    uint4 pk;
    pk.x = packbf(r4.x, r4.y);
    pk.y = packbf(r4.z, r4.w);
    pk.z = packbf(ww * r4.x, ww * r4.y);
    pk.w = packbf(ww * r4.z, ww * r4.w);
    *(uint4*)((unsigned*)ws + WS_V2 + bn * 4) = pk;
  }
  float p = prec[bn];
  float vals[8] = {p * r4.x, p * r4.y, p * r4.z, p * r4.w,
                   ww * r4.x, ww * r4.y, ww * r4.z, ww * r4.w};
  #pragma unroll
  for (int k = 0; k < 8; ++k) {
    float v = vals[k];
    #pragma unroll
    for (int s = 32; s; s >>= 1) v += __shfl_xor(v, s);
    vals[k] = v;
  }
  if (lane == 0) {
    #pragma unroll
    for (int k = 0; k < 8; ++k) red8[wv][k] = vals[k];
  }
  const float* Mrow = mem + bn * WDIM;
  float* Orow = omem + bn * WDIM;
  float dr0 = 0.f, dr1 = 0.f, dr2 = 0.f, dr3 = 0.f, ssqn = 0.f;
  #pragma unroll
  for (int w4 = 0; w4 < 16; ++w4) {
    float4 m4 = *(const float4*)(Mrow + (w4 << 2));
    float4 e4 = *(const float4*)(&shev[w4 << 2]);
    float4 wv4 = *(const float4*)(&shev[64 + (w4 << 2)]);
    float4 o;
    o.x = m4.x * (1.0f - ww * e4.x) + ww * wv4.x;
    o.y = m4.y * (1.0f - ww * e4.y) + ww * wv4.y;
    o.z = m4.z * (1.0f - ww * e4.z) + ww * wv4.z;
    o.w = m4.w * (1.0f - ww * e4.w) + ww * wv4.w;
    *(float4*)(Orow + (w4 << 2)) = o;
    ssqn += o.x * o.x + o.y * o.y + o.z * o.z + o.w * o.w;
    float4 k0 = *(const float4*)(&kn[w4 << 2]);
    float4 k1 = *(const float4*)(&kn[64 + (w4 << 2)]);
    float4 k2 = *(const float4*)(&kn[128 + (w4 << 2)]);
    float4 k3 = *(const float4*)(&kn[192 + (w4 << 2)]);
    dr0 += o.x * k0.x + o.y * k0.y + o.z * k0.z + o.w * k0.w;
    dr1 += o.x * k1.x + o.y * k1.y + o.z * k1.z + o.w * k1.w;
    dr2 += o.x * k2.x + o.y * k2.y + o.z * k2.z + o.w * k2.w;
    dr3 += o.x * k3.x + o.y * k3.y + o.z * k3.z + o.w * k3.w;
  }
  float rs = rsqrtf(ssqn + EPSF);
  float er[4] = {expf(dr0 * rs * f[IF_RSTR + 0]), expf(dr1 * rs * f[IF_RSTR + 1]),
                 expf(dr2 * rs * f[IF_RSTR + 2]), expf(dr3 * rs * f[IF_RSTR + 3])};
  float4 er4 = {er[0], er[1], er[2], er[3]};
  *(float4*)(ws + WS_ER + bn * 4) = er4;
  #pragma unroll
  for (int r = 0; r < 4; ++r) {
    float v = er[r];
    #pragma unroll
    for (int s = 32; s; s >>= 1) v += __shfl_xor(v, s);
    er[r] = v;
  }
  if (lane == 0) {
    #pragma unroll
    for (int r = 0; r < 4; ++r) red4[wv][r] = er[r];
  }
  __syncthreads();
  if (t < 8)
    ws[WS_STP + (((q << 6) + b) << 3) + t] =
        red8[0][t] + red8[1][t] + red8[2][t] + red8[3][t];
  else if (t >= 64 && t < 68)
    ws[WS_ERP + (((q << 6) + b) << 2) + (t - 64)] =
        red4[0][t - 64] + red4[1][t - 64] + red4[2][t - 64] + red4[3][t - 64];
}

// 7) link pass v8: bf16-packed broadcast operands — one uniform b128 carries
//    all 8 v/u values (halves LDS broadcast traffic). Counted-vmcnt pipeline,
//    conflict-free col pass, 256-thread blocks, grid (16,64).
__global__ __launch_bounds__(256, 4) void k_link(const float* __restrict__ link,
                                                 float* __restrict__ ws) {
  __shared__ float buf[2][4096];      // [2][64][64] swizzled link tiles (32KB)
  __shared__ unsigned vtile[2][256];  // [2][64][4] u32 (2KB)
  __shared__ unsigned ublk[256];      // [64][4] u32 (1KB)
  __shared__ float scr[512];          // [8][64] (2KB)
  const int rg = blockIdx.x, b = blockIdx.y;   // rg 0..15
  const int wv = threadIdx.x >> 6, lane = threadIdx.x & 63;
  const int i0 = rg << 6;
  const int rot = ((rg << 1) + b) & 15;
  const float* L = link + ((size_t)b << 20) + ((size_t)i0 << 10);
  const float* V2f = ws + WS_V2 + ((size_t)b << 12);

  const float* gsrc[4];
  #pragma unroll
  for (int s = 0; s < 4; ++s) {
    const int qq = (wv << 2) + s;
    const int row = (qq << 2) + (lane >> 4);
    const int cb = (lane & 15) ^ (row & 15);
    gsrc[s] = L + (size_t)row * 1024 + (cb << 2);
  }

  float rowAcc[8], colAcc[8];
  #pragma unroll
  for (int k = 0; k < 8; ++k) { rowAcc[k] = 0.0f; colAcc[k] = 0.0f; }

  // prologue: tile rot + vtile rot + ublk, full drain once
  {
    const int c0 = rot << 6;
    #pragma unroll
    for (int s = 0; s < 4; ++s) gl16(gsrc[s] + c0, &buf[0][((wv << 2) + s) << 8]);
    if (wv == 0) gl16(V2f + ((c0 + lane) << 2), (float*)&vtile[0][0]);
    if (wv == 2) gl16(V2f + ((i0 + lane) << 2), (float*)&ublk[0]);
  }
  __syncthreads();

  int p = 0;
  #pragma unroll 1
  for (int jt = 0; jt < 16; ++jt) {
    const int jcur = ((jt + rot) & 15);
    // A) issue next-tile loads; counted wait keeps them in flight
    if (jt < 15) {
      const int jn = ((jt + 1 + rot) & 15) << 6;
      #pragma unroll
      for (int s = 0; s < 4; ++s)
        gl16(gsrc[s] + jn, &buf[p ^ 1][((wv << 2) + s) << 8]);
      if (wv == 0) {
        gl16(V2f + ((jn + lane) << 2), (float*)&vtile[p ^ 1][0]);
        asm volatile("s_waitcnt vmcnt(5)" ::: "memory");
      } else {
        asm volatile("s_waitcnt vmcnt(4)" ::: "memory");
      }
    } else {
      asm volatile("s_waitcnt vmcnt(0)" ::: "memory");
    }
    __builtin_amdgcn_sched_barrier(0);
    __builtin_amdgcn_s_barrier();        // barA: buf[p]/vtile[p] ready
    __builtin_amdgcn_sched_barrier(0);
    // B) compute on buf[p]
    const float* tb = &buf[p][0];
    if (wv < 2) {
      // row pass: lane = row, wv = column half
      const float* base = tb + (lane << 6);
      const int rm = lane & 15;
      const unsigned* vt = &vtile[p][0];
      #pragma unroll
      for (int jb8 = 0; jb8 < 8; ++jb8) {
        const int jb = (wv << 3) + jb8;
        float4 f4 = *(const float4*)(base + ((jb ^ rm) << 2));
        #pragma unroll
        for (int q = 0; q < 4; ++q) {
          float fq = (q == 0) ? f4.x : (q == 1) ? f4.y : (q == 2) ? f4.z : f4.w;
          const uint4 vq = *(const uint4*)(vt + (((jb << 2) + q) << 2));
          rowAcc[0] = fmaf(fq, blo(vq.x), rowAcc[0]);
          rowAcc[1] = fmaf(fq, bhi(vq.x), rowAcc[1]);
          rowAcc[2] = fmaf(fq, blo(vq.y), rowAcc[2]);
          rowAcc[3] = fmaf(fq, bhi(vq.y), rowAcc[3]);
          rowAcc[4] = fmaf(fq, blo(vq.z), rowAcc[4]);
          rowAcc[5] = fmaf(fq, bhi(vq.z), rowAcc[5]);
          rowAcc[6] = fmaf(fq, blo(vq.w), rowAcc[6]);
          rowAcc[7] = fmaf(fq, bhi(vq.w), rowAcc[7]);
        }
      }
    } else {
      // col pass: lane = column, wv-2 = row half (32 rows)
      const int iq = wv - 2;
      #pragma unroll 8
      for (int ii = 0; ii < 32; ++ii) {
        const int i = (iq << 5) + ii;
        float fq = tb[(i << 6) + ((((lane >> 2) ^ (i & 15)) << 2) | (lane & 3))];
        const uint4 uq = *(const uint4*)(&ublk[i << 2]);   // uniform broadcast
        colAcc[0] = fmaf(fq, blo(uq.x), colAcc[0]);
        colAcc[1] = fmaf(fq, bhi(uq.x), colAcc[1]);
        colAcc[2] = fmaf(fq, blo(uq.y), colAcc[2]);
        colAcc[3] = fmaf(fq, bhi(uq.y), colAcc[3]);
        colAcc[4] = fmaf(fq, blo(uq.z), colAcc[4]);
        colAcc[5] = fmaf(fq, bhi(uq.z), colAcc[5]);
        colAcc[6] = fmaf(fq, blo(uq.w), colAcc[6]);
        colAcc[7] = fmaf(fq, bhi(uq.w), colAcc[7]);
      }
      if (wv == 3) {
        #pragma unroll
        for (int k = 0; k < 8; ++k) scr[(k << 6) + lane] = colAcc[k];
      }
    }
    // C) publish scr (LDS only), cross barB with prefetch still in flight
    asm volatile("s_waitcnt lgkmcnt(0)" ::: "memory");
    __builtin_amdgcn_s_barrier();        // barB
    __builtin_amdgcn_sched_barrier(0);
    if (wv == 2) {
      float* cp = ws + WS_COLPART + ((((size_t)rg << 6) + (size_t)b) << 13) +
                  (size_t)((jcur << 6) + lane) * 8;
      float s[8];
      #pragma unroll
      for (int k = 0; k < 8; ++k) s[k] = colAcc[k] + scr[(k << 6) + lane];
      float4 c0 = {s[0], s[1], s[2], s[3]};
      float4 c1 = {s[4], s[5], s[6], s[7]};
      *(float4*)cp = c0;
      *(float4*)(cp + 4) = c1;
    }
    if (wv >= 2) {
      #pragma unroll
      for (int k = 0; k < 8; ++k) colAcc[k] = 0.0f;
    }
    p ^= 1;
  }

  // epilogue: combine row column-halves (wv0 + wv1)
  __syncthreads();
  if (wv == 1) {
    #pragma unroll
    for (int k = 0; k < 8; ++k) buf[0][(lane << 3) + k] = rowAcc[k];
  }
  __syncthreads();
  if (wv == 0) {
    float* rp = ws + WS_ROWAB + ((size_t)(b << 10) + i0 + lane) * 8;
    #pragma unroll
    for (int k = 0; k < 8; ++k) rowAcc[k] += buf[0][(lane << 3) + k];
    float4 c0 = {rowAcc[0], rowAcc[1], rowAcc[2], rowAcc[3]};
    float4 c1 = {rowAcc[4], rowAcc[5], rowAcc[6], rowAcc[7]};
    *(float4*)rp = c0;
    *(float4*)(rp + 4) = c1;
  }
}

// 8) final combine: grid (4,64), no barriers; sums 16 col partials
__global__ __launch_bounds__(256) void k_final(const float* __restrict__ rw,
                                               const float* __restrict__ prec,
                                               const float* __restrict__ ws,
                                               float* __restrict__ orw) {
  const int q = blockIdx.x, b = blockIdx.y, t = threadIdx.x;
  const float* f = ws + WS_IFACE + (size_t)b * IF_STRIDE;
  float denom[4], ST[8];
  #pragma unroll
  for (int r = 0; r < 4; ++r)
    denom[r] = ws[WS_ERP + (b << 2) + r] + ws[WS_ERP + ((64 + b) << 2) + r] +
               ws[WS_ERP + ((128 + b) << 2) + r] + ws[WS_ERP + ((192 + b) << 2) + r];
  #pragma unroll
  for (int k = 0; k < 8; ++k)
    ST[k] = ws[WS_STP + (b << 3) + k] + ws[WS_STP + ((64 + b) << 3) + k] +
            ws[WS_STP + ((128 + b) << 3) + k] + ws[WS_STP + ((192 + b) << 3) + k];
  const int n = (q << 8) + t;
  const size_t bn = (size_t)(b << 10) + n;
  float4 er4 = *(const float4*)(ws + WS_ER + bn * 4);
  float cr[4] = {er4.x / denom[0], er4.y / denom[1], er4.z / denom[2], er4.w / denom[3]};
  float ca[8];
  #pragma unroll
  for (int k = 0; k < 8; ++k) ca[k] = 0.0f;
  #pragma unroll
  for (int rg = 0; rg < 16; ++rg) {
    const float* p = ws + WS_COLPART + ((((size_t)rg << 6) + (size_t)b) << 13) +
                     (size_t)n * 8;
    float4 a = *(const float4*)p;
    float4 c2 = *(const float4*)(p + 4);
    ca[0] += a.x; ca[1] += a.y; ca[2] += a.z; ca[3] += a.w;
    ca[4] += c2.x; ca[5] += c2.y; ca[6] += c2.z; ca[7] += c2.w;
  }
  const float* ra = ws + WS_ROWAB + bn * 8;
  float d = ws[WS_DIAG + bn];
  float w_ = ws[WS_WW + bn];
  float pn = prec[bn];
  float4 r4 = *(const float4*)(rw + bn * 4);
  float rv[4] = {r4.x, r4.y, r4.z, r4.w};
  float ow = 1.0f - w_;
  float res[4];
  #pragma unroll
  for (int r = 0; r < 4; ++r) {
    float A = ra[r], Ap = ra[4 + r], Bv = ca[r], Bp = ca[4 + r];
    float fwd = ow * (A - d * rv[r]) - (Ap - w_ * d * rv[r]) + w_ * (ST[r] - pn * rv[r]);
    float bwd = ow * (Bv - d * rv[r]) - (Bp - w_ * d * rv[r]) + pn * (ST[4 + r] - w_ * rv[r]);
    res[r] = f[IF_MODES + r * 3] * bwd + f[IF_MODES + r * 3 + 1] * cr[r] +
             f[IF_MODES + r * 3 + 2] * fwd;
  }
  float4 o = {res[0], res[1], res[2], res[3]};
  *(float4*)(orw + bn * 4) = o;
}

extern "C" void kernel_launch(void* const* d_in, const int* in_sizes, int n_in,
                              void* d_out, int out_size, void* d_ws, size_t ws_size,
                              hipStream_t stream) {
  const float* x     = (const float*)d_in[0];
  const float* rw    = (const float*)d_in[1];
  const float* mem   = (const float*)d_in[2];
  const float* usage = (const float*)d_in[3];
  const float* wwp   = (const float*)d_in[4];
  const float* link  = (const float*)d_in[5];
  const float* prec  = (const float*)d_in[6];
  const float* W1    = (const float*)d_in[7];
  const float* b1    = (const float*)d_in[8];
  const float* Wo    = (const float*)d_in[9];
  const float* bo    = (const float*)d_in[10];
  const float* Wr    = (const float*)d_in[11];
  const float* br    = (const float*)d_in[12];
  const float* Wxi   = (const float*)d_in[13];
  const float* bxi   = (const float*)d_in[14];
  float* out = (float*)d_out;
  float* ws = (float*)d_ws;

  k_read_flat<<<dim3(4, 64), 1024, 0, stream>>>(mem, rw, ws);
  k_h<<<dim3(2, 64), 256, 0, stream>>>(x, W1, b1, ws);
  k_xiout<<<dim3(3, 64), 256, 0, stream>>>(Wxi, bxi, Wo, bo, Wr, br, ws, out);
  k_iface<<<64, 64, 0, stream>>>(out, ws);
  k_allocwc<<<dim3(8, 64), 256, 0, stream>>>(rw, usage, wwp, mem, link, ws, out + O_USAGE);
  k_wcww_b<<<dim3(4, 64), 256, 0, stream>>>(mem, rw, prec, ws, out + O_MEM);
  k_link<<<dim3(16, 64), 256, 0, stream>>>(link, ws);
  k_final<<<dim3(4, 64), 256, 0, stream>>>(rw, prec, ws, out + O_RW);
}

// Round 13
// 243.585 us; speedup vs baseline: 1.1018x; 1.1018x over previous
//
#include <hip/hip_runtime.h>

#define NB 64
#define NN 1024
#define WDIM 64
#define RR 4
#define HID 512
#define XID 471
#define EPSF 1e-6f

// ---- d_out offsets (floats) ----
#define O_OUT   0
#define O_XI    16384
#define O_RW    46528
#define O_MEM   308672
#define O_USAGE 4502976

// ---- ws offsets (floats) ----
#define WS_RFPART   0          // [4][64][256] read_flat partials
#define WS_H        65536      // [64][512]
#define WS_ALLOC    129024     // [64][1024]
#define WS_WW       194560     // [64][1024]
#define WS_V        260096     // [64][1024][8]
#define WS_DIAG     784896     // [64][1024]
#define WS_ROWAB    850432     // [64][1024][8]
#define WS_COLPART  1899008    // [16][64][1024][8] col partials (33.5 MB)
#define WS_EW       10287616   // [4][64]
#define WS_SIMWE    10287872   // [64][1024]
#define WS_ERP      10353408   // [4][64][4]
#define WS_ER       10354432   // [64][1024][4]
#define WS_STP      10616576   // [4][64][8]

__device__ __forceinline__ float sigmoidf_(float x) { return 1.0f / (1.0f + expf(-x)); }
__device__ __forceinline__ float oneplusf_(float x) {
  return 1.0f + ((x > 20.0f) ? x : log1pf(expf(x)));
}

typedef const __attribute__((address_space(1))) void gas_void;
typedef __attribute__((address_space(3))) void las_void;
__device__ __forceinline__ void gl16(const float* g, float* l) {
  __builtin_amdgcn_global_load_lds((gas_void*)g, (las_void*)l, 16, 0, 0);
}

// 1) read_flat partials
__global__ __launch_bounds__(1024) void k_read_flat(const float* __restrict__ mem,
                                                    const float* __restrict__ rw,
                                                    float* __restrict__ ws) {
  __shared__ float red[1024];
  const int q = blockIdx.x, b = blockIdx.y, t = threadIdx.x;
  const int rwi = t & 255;
  const int r = rwi >> 6, w = rwi & 63;
  const int ng = t >> 8;
  const int n0 = (q << 8) + (ng << 6);
  const float* M  = mem + ((size_t)(b << 10) + n0) * WDIM;
  const float* Rw = rw  + ((size_t)(b << 10) + n0) * RR;
  float a0 = 0.f, a1 = 0.f, a2 = 0.f, a3 = 0.f;
  for (int n = 0; n < 64; n += 4) {
    a0 += M[(n + 0) * WDIM + w] * Rw[(n + 0) * RR + r];
    a1 += M[(n + 1) * WDIM + w] * Rw[(n + 1) * RR + r];
    a2 += M[(n + 2) * WDIM + w] * Rw[(n + 2) * RR + r];
    a3 += M[(n + 3) * WDIM + w] * Rw[(n + 3) * RR + r];
  }
  red[t] = (a0 + a1) + (a2 + a3);
  __syncthreads();
  if (t < 256)
    ws[WS_RFPART + (((q << 6) + b) << 8) + t] =
        red[t] + red[t + 256] + red[t + 512] + red[t + 768];
}

// 2) h = relu([x, read_flat] @ W1 + b1), col-split grid (2,64); 4-acc ILP
__global__ __launch_bounds__(256) void k_h(const float* __restrict__ x,
                                           const float* __restrict__ W1,
                                           const float* __restrict__ b1,
                                           float* __restrict__ ws) {
  __shared__ float cat[768];
  const int ch = blockIdx.x, b = blockIdx.y, t = threadIdx.x;
  cat[t] = x[b * 512 + t];
  cat[256 + t] = x[b * 512 + 256 + t];
  {
    float s = 0.0f;
    #pragma unroll
    for (int q = 0; q < 4; ++q) s += ws[WS_RFPART + (((q << 6) + b) << 8) + t];
    cat[512 + t] = s;
  }
  __syncthreads();
  const int col = (ch << 8) + t;
  float a0 = 0.f, a1 = 0.f, a2 = 0.f, a3 = 0.f;
  #pragma unroll 4
  for (int k = 0; k < 768; k += 4) {
    a0 = fmaf(cat[k + 0], W1[(k + 0) * 512 + col], a0);
    a1 = fmaf(cat[k + 1], W1[(k + 1) * 512 + col], a1);
    a2 = fmaf(cat[k + 2], W1[(k + 2) * 512 + col], a2);
    a3 = fmaf(cat[k + 3], W1[(k + 3) * 512 + col], a3);
  }
  ws[WS_H + b * 512 + col] = fmaxf(b1[col] + (a0 + a1) + (a2 + a3), 0.0f);
}

// 3) xi (blocks 0,1) and output (block 2), grid (3,64); 4-acc ILP
__global__ __launch_bounds__(256) void k_xiout(const float* __restrict__ Wxi,
                                               const float* __restrict__ bxi,
                                               const float* __restrict__ Wo,
                                               const float* __restrict__ bo,
                                               const float* __restrict__ Wr,
                                               const float* __restrict__ br,
                                               const float* __restrict__ ws,
                                               float* __restrict__ out) {
  __shared__ float h[512];
  __shared__ float rf[256];
  const int m = blockIdx.x, b = blockIdx.y, t = threadIdx.x;
  h[t] = ws[WS_H + b * 512 + t];
  h[256 + t] = ws[WS_H + b * 512 + 256 + t];
  if (m == 2) {
    float s = 0.0f;
    #pragma unroll
    for (int q = 0; q < 4; ++q) s += ws[WS_RFPART + (((q << 6) + b) << 8) + t];
    rf[t] = s;
  }
  __syncthreads();
  if (m < 2) {
    const int col = (m << 8) + t;
    if (col < XID) {
      float a0 = 0.f, a1 = 0.f, a2 = 0.f, a3 = 0.f;
      #pragma unroll 4
      for (int j = 0; j < 512; j += 4) {
        a0 = fmaf(h[j + 0], Wxi[(j + 0) * XID + col], a0);
        a1 = fmaf(h[j + 1], Wxi[(j + 1) * XID + col], a1);
        a2 = fmaf(h[j + 2], Wxi[(j + 2) * XID + col], a2);
        a3 = fmaf(h[j + 3], Wxi[(j + 3) * XID + col], a3);
      }
      out[O_XI + b * XID + col] = bxi[col] + (a0 + a1) + (a2 + a3);
    }
  } else {
    float a0 = 0.f, a1 = 0.f, a2 = 0.f, a3 = 0.f;
    #pragma unroll 4
    for (int j = 0; j < 512; j += 4) {
      a0 = fmaf(h[j + 0], Wo[(j + 0) * 256 + t], a0);
      a1 = fmaf(h[j + 1], Wo[(j + 1) * 256 + t], a1);
      a2 = fmaf(h[j + 2], Wo[(j + 2) * 256 + t], a2);
      a3 = fmaf(h[j + 3], Wo[(j + 3) * 256 + t], a3);
    }
    #pragma unroll 4
    for (int j = 0; j < 256; j += 4) {
      a0 = fmaf(rf[j + 0], Wr[(j + 0) * 256 + t], a0);
      a1 = fmaf(rf[j + 1], Wr[(j + 1) * 256 + t], a1);
      a2 = fmaf(rf[j + 2], Wr[(j + 2) * 256 + t], a2);
      a3 = fmaf(rf[j + 3], Wr[(j + 3) * 256 + t], a3);
    }
    out[O_OUT + b * 256 + t] = bo[t] + br[t] + (a0 + a1) + (a2 + a3);
  }
}

// 4) fused: blocks 0-3 usage_new+allocation; blocks 4-7 write-content exp+diag
//    (interface pieces recomputed in-block from xi — k_iface eliminated)
__global__ __launch_bounds__(256) void k_allocwc(const float* __restrict__ rw,
                                                 const float* __restrict__ usage,
                                                 const float* __restrict__ wwp,
                                                 const float* __restrict__ mem,
                                                 const float* __restrict__ link,
                                                 float* __restrict__ ws,
                                                 float* __restrict__ out) {
  __shared__ float ua[1024];
  __shared__ float la[1024];
  __shared__ float wkn[64];
  __shared__ float red[4];
  __shared__ float swstr;
  const int z = blockIdx.x, b = blockIdx.y, t = threadIdx.x;
  const float* xi = out + O_XI + b * XID;
  if (z < 4) {
    const int q = z;
    const float f0 = sigmoidf_(xi[453]), f1 = sigmoidf_(xi[454]);
    const float f2 = sigmoidf_(xi[455]), f3 = sigmoidf_(xi[456]);
    #pragma unroll
    for (int c = 0; c < 4; ++c) {
      const int n = (c << 8) + t;
      const int i = (b << 10) + n;
      const float4 r4 = *(const float4*)(rw + (size_t)i * 4);
      float ret = (1.0f - f0 * r4.x) * (1.0f - f1 * r4.y) *
                  (1.0f - f2 * r4.z) * (1.0f - f3 * r4.w);
      float u = usage[i], w = wwp[i];
      float un = (u + w - u * w) * ret;
      if (c == q) out[O_USAGE + i] = un;
      ua[n] = un;
      la[n] = logf(un);
    }
    __syncthreads();
    const int i = (q << 8) + t;
    const float ui = ua[i];
    float s0 = 0.f, s1 = 0.f, s2 = 0.f, s3 = 0.f;
    #pragma unroll 2
    for (int j = 0; j < 1024; j += 4) {
      float4 u4 = *(const float4*)(ua + j);
      float4 l4 = *(const float4*)(la + j);
      s0 += ((u4.x < ui) || (u4.x == ui && j + 0 < i)) ? l4.x : 0.0f;
      s1 += ((u4.y < ui) || (u4.y == ui && j + 1 < i)) ? l4.y : 0.0f;
      s2 += ((u4.z < ui) || (u4.z == ui && j + 2 < i)) ? l4.z : 0.0f;
      s3 += ((u4.w < ui) || (u4.w == ui && j + 3 < i)) ? l4.w : 0.0f;
    }
    ws[WS_ALLOC + (b << 10) + i] = (1.0f - ui) * expf((s0 + s1) + (s2 + s3));
  } else {
    const int q = z - 4;
    const int wv = t >> 6, lane = t & 63;
    if (t < 64) {
      float kv = xi[260 + t];
      float ss = kv * kv;
      #pragma unroll
      for (int s = 32; s; s >>= 1) ss += __shfl_xor(ss, s);
      wkn[t] = kv * rsqrtf(ss + EPSF);
    }
    if (t == 64) swstr = oneplusf_(xi[324]);
    __syncthreads();
    const int n = (q << 8) + t;
    const size_t bn = (size_t)(b << 10) + n;
    const float* Mrow = mem + bn * WDIM;
    float dot = 0.0f, ssq = 0.0f;
    #pragma unroll
    for (int w = 0; w < 64; w += 4) {
      float4 m4 = *(const float4*)(Mrow + w);
      float4 k4 = *(const float4*)(&wkn[w]);
      dot += m4.x * k4.x + m4.y * k4.y + m4.z * k4.z + m4.w * k4.w;
      ssq += m4.x * m4.x + m4.y * m4.y + m4.z * m4.z + m4.w * m4.w;
    }
    float e = expf(dot * rsqrtf(ssq + EPSF) * swstr);
    ws[WS_SIMWE + bn] = e;
    ws[WS_DIAG + bn] = link[bn * 1024 + n];
    float se = e;
    #pragma unroll
    for (int s = 32; s; s >>= 1) se += __shfl_xor(se, s);
    if (lane == 0) red[wv] = se;
    __syncthreads();
    if (t == 0) ws[WS_EW + (q << 6) + b] = red[0] + red[1] + red[2] + red[3];
  }
}

// 5) ww + V + ST partials + memory_new + fused read-content exp + partials
//    (interface pieces recomputed in-block from xi)
__global__ __launch_bounds__(256) void k_wcww_b(const float* __restrict__ mem,
                                                const float* __restrict__ rw,
                                                const float* __restrict__ prec,
                                                float* __restrict__ ws,
                                                float* __restrict__ out) {
  __shared__ float kn[256];
  __shared__ float shev[128];
  __shared__ float smisc[8];   // rstr[0..3], ag, wg
  __shared__ float red8[4][8];
  __shared__ float red4[4][4];
  const int q = blockIdx.x, b = blockIdx.y, t = threadIdx.x;
  const int wv = t >> 6, lane = t & 63;
  const float* xi = out + O_XI + b * XID;
  {
    float kv = xi[(wv << 6) + lane];
    float ss = kv * kv;
    #pragma unroll
    for (int s = 32; s; s >>= 1) ss += __shfl_xor(ss, s);
    kn[t] = kv * rsqrtf(ss + EPSF);
  }
  if (t < 64) shev[t] = sigmoidf_(xi[325 + t]);
  else if (t < 128) shev[t] = xi[389 + (t - 64)];
  else if (t < 132) smisc[t - 128] = oneplusf_(xi[256 + (t - 128)]);
  else if (t == 132) smisc[4] = sigmoidf_(xi[457]);
  else if (t == 133) smisc[5] = sigmoidf_(xi[458]);
  __syncthreads();
  const float denom = ws[WS_EW + b] + ws[WS_EW + 64 + b] +
                      ws[WS_EW + 128 + b] + ws[WS_EW + 192 + b];
  const int n = (q << 8) + t;
  const size_t bn = (size_t)(b << 10) + n;
  float wc = ws[WS_SIMWE + bn] / denom;
  float ag = smisc[4], wg = smisc[5];
  float ww = wg * (ag * ws[WS_ALLOC + bn] + (1.0f - ag) * wc);
  ws[WS_WW + bn] = ww;
  float4 r4 = *(const float4*)(rw + bn * 4);
  float* vp = ws + WS_V + bn * 8;
  float4 v0 = {r4.x, r4.y, r4.z, r4.w};
  float4 v1 = {ww * r4.x, ww * r4.y, ww * r4.z, ww * r4.w};
  *(float4*)vp = v0;
  *(float4*)(vp + 4) = v1;
  float p = prec[bn];
  float vals[8] = {p * r4.x, p * r4.y, p * r4.z, p * r4.w,
                   ww * r4.x, ww * r4.y, ww * r4.z, ww * r4.w};
  #pragma unroll
  for (int k = 0; k < 8; ++k) {
    float v = vals[k];
    #pragma unroll
    for (int s = 32; s; s >>= 1) v += __shfl_xor(v, s);
    vals[k] = v;
  }
  if (lane == 0) {
    #pragma unroll
    for (int k = 0; k < 8; ++k) red8[wv][k] = vals[k];
  }
  const float* Mrow = mem + bn * WDIM;
  float* Orow = out + O_MEM + bn * WDIM;
  float dr0 = 0.f, dr1 = 0.f, dr2 = 0.f, dr3 = 0.f, ssqn = 0.f;
  #pragma unroll
  for (int w4 = 0; w4 < 16; ++w4) {
    float4 m4 = *(const float4*)(Mrow + (w4 << 2));
    float4 e4 = *(const float4*)(&shev[w4 << 2]);
    float4 wv4 = *(const float4*)(&shev[64 + (w4 << 2)]);
    float4 o;
    o.x = m4.x * (1.0f - ww * e4.x) + ww * wv4.x;
    o.y = m4.y * (1.0f - ww * e4.y) + ww * wv4.y;
    o.z = m4.z * (1.0f - ww * e4.z) + ww * wv4.z;
    o.w = m4.w * (1.0f - ww * e4.w) + ww * wv4.w;
    *(float4*)(Orow + (w4 << 2)) = o;
    ssqn += o.x * o.x + o.y * o.y + o.z * o.z + o.w * o.w;
    float4 k0 = *(const float4*)(&kn[w4 << 2]);
    float4 k1 = *(const float4*)(&kn[64 + (w4 << 2)]);
    float4 k2 = *(const float4*)(&kn[128 + (w4 << 2)]);
    float4 k3 = *(const float4*)(&kn[192 + (w4 << 2)]);
    dr0 += o.x * k0.x + o.y * k0.y + o.z * k0.z + o.w * k0.w;
    dr1 += o.x * k1.x + o.y * k1.y + o.z * k1.z + o.w * k1.w;
    dr2 += o.x * k2.x + o.y * k2.y + o.z * k2.z + o.w * k2.w;
    dr3 += o.x * k3.x + o.y * k3.y + o.z * k3.z + o.w * k3.w;
  }
  float rs = rsqrtf(ssqn + EPSF);
  float er[4] = {expf(dr0 * rs * smisc[0]), expf(dr1 * rs * smisc[1]),
                 expf(dr2 * rs * smisc[2]), expf(dr3 * rs * smisc[3])};
  float4 er4 = {er[0], er[1], er[2], er[3]};
  *(float4*)(ws + WS_ER + bn * 4) = er4;
  #pragma unroll
  for (int r = 0; r < 4; ++r) {
    float v = er[r];
    #pragma unroll
    for (int s = 32; s; s >>= 1) v += __shfl_xor(v, s);
    er[r] = v;
  }
  if (lane == 0) {
    #pragma unroll
    for (int r = 0; r < 4; ++r) red4[wv][r] = er[r];
  }
  __syncthreads();
  if (t < 8)
    ws[WS_STP + (((q << 6) + b) << 3) + t] =
        red8[0][t] + red8[1][t] + red8[2][t] + red8[3][t];
  else if (t >= 64 && t < 68)
    ws[WS_ERP + (((q << 6) + b) << 2) + (t - 64)] =
        red4[0][t - 64] + red4[1][t - 64] + red4[2][t - 64] + red4[3][t - 64];
}

// 6) link pass (r11 v7, verified best): counted-vmcnt pipeline, conflict-free
//    col pass (2 lanes/bank), 256-thread blocks, grid (16,64), 40KB LDS.
__global__ __launch_bounds__(256, 4) void k_link(const float* __restrict__ link,
                                                 float* __restrict__ ws) {
  __shared__ float buf[2][4096];    // [2][64][64] swizzled link tiles (32KB)
  __shared__ float vtile[2][512];   // [2][64][8]  (4KB)
  __shared__ float ublk[512];       // [64][8]     (2KB)
  __shared__ float scr[512];        // [8][64]     (2KB)
  const int rg = blockIdx.x, b = blockIdx.y;   // rg 0..15
  const int wv = threadIdx.x >> 6, lane = threadIdx.x & 63;
  const int i0 = rg << 6;
  const int rot = ((rg << 1) + b) & 15;
  const float* L = link + ((size_t)b << 20) + ((size_t)i0 << 10);
  const float* V = ws + WS_V + ((size_t)b << 13);

  const float* gsrc[4];
  #pragma unroll
  for (int s = 0; s < 4; ++s) {
    const int qq = (wv << 2) + s;
    const int row = (qq << 2) + (lane >> 4);
    const int cb = (lane & 15) ^ (row & 15);
    gsrc[s] = L + (size_t)row * 1024 + (cb << 2);
  }

  float rowAcc[8], colAcc[8];
  #pragma unroll
  for (int k = 0; k < 8; ++k) { rowAcc[k] = 0.0f; colAcc[k] = 0.0f; }

  {
    const int c0 = rot << 6;
    #pragma unroll
    for (int s = 0; s < 4; ++s) gl16(gsrc[s] + c0, &buf[0][((wv << 2) + s) << 8]);
    if (wv < 2) gl16(V + ((size_t)c0 << 3) + (wv << 8) + (lane << 2), &vtile[0][wv << 8]);
    else        gl16(V + ((size_t)(i0 + ((wv - 2) << 5)) << 3) + (lane << 2),
                     &ublk[(wv - 2) << 8]);
  }
  __syncthreads();

  int p = 0;
  #pragma unroll 1
  for (int jt = 0; jt < 16; ++jt) {
    const int jcur = ((jt + rot) & 15);
    if (jt < 15) {
      const int jn = ((jt + 1 + rot) & 15) << 6;
      #pragma unroll
      for (int s = 0; s < 4; ++s)
        gl16(gsrc[s] + jn, &buf[p ^ 1][((wv << 2) + s) << 8]);
      if (wv < 2) {
        gl16(V + ((size_t)jn << 3) + (wv << 8) + (lane << 2), &vtile[p ^ 1][wv << 8]);
        asm volatile("s_waitcnt vmcnt(5)" ::: "memory");
      } else {
        asm volatile("s_waitcnt vmcnt(4)" ::: "memory");
      }
    } else {
      asm volatile("s_waitcnt vmcnt(0)" ::: "memory");
    }
    __builtin_amdgcn_sched_barrier(0);
    __builtin_amdgcn_s_barrier();        // barA: buf[p]/vtile[p] ready
    __builtin_amdgcn_sched_barrier(0);
    const float* tb = &buf[p][0];
    if (wv < 2) {
      const float* base = tb + (lane << 6);
      const int rm = lane & 15;
      const float* vt = &vtile[p][0];
      #pragma unroll
      for (int jb8 = 0; jb8 < 8; ++jb8) {
        const int jb = (wv << 3) + jb8;
        float4 f4 = *(const float4*)(base + ((jb ^ rm) << 2));
        const float* vsb = vt + (jb << 5);
        #pragma unroll
        for (int q = 0; q < 4; ++q) {
          float fq = (q == 0) ? f4.x : (q == 1) ? f4.y : (q == 2) ? f4.z : f4.w;
          float4 a = *(const float4*)(vsb + (q << 3));
          float4 c = *(const float4*)(vsb + (q << 3) + 4);
          rowAcc[0] = fmaf(fq, a.x, rowAcc[0]);
          rowAcc[1] = fmaf(fq, a.y, rowAcc[1]);
          rowAcc[2] = fmaf(fq, a.z, rowAcc[2]);
          rowAcc[3] = fmaf(fq, a.w, rowAcc[3]);
          rowAcc[4] = fmaf(fq, c.x, rowAcc[4]);
          rowAcc[5] = fmaf(fq, c.y, rowAcc[5]);
          rowAcc[6] = fmaf(fq, c.z, rowAcc[6]);
          rowAcc[7] = fmaf(fq, c.w, rowAcc[7]);
        }
      }
    } else {
      const int iq = wv - 2;
      #pragma unroll 8
      for (int ii = 0; ii < 32; ++ii) {
        const int i = (iq << 5) + ii;
        float fq = tb[(i << 6) + ((((lane >> 2) ^ (i & 15)) << 2) | (lane & 3))];
        const float* ur = &ublk[i << 3];   // wave-uniform -> broadcast
        float4 a = *(const float4*)ur;
        float4 cc = *(const float4*)(ur + 4);
        colAcc[0] = fmaf(fq, a.x, colAcc[0]);
        colAcc[1] = fmaf(fq, a.y, colAcc[1]);
        colAcc[2] = fmaf(fq, a.z, colAcc[2]);
        colAcc[3] = fmaf(fq, a.w, colAcc[3]);
        colAcc[4] = fmaf(fq, cc.x, colAcc[4]);
        colAcc[5] = fmaf(fq, cc.y, colAcc[5]);
        colAcc[6] = fmaf(fq, cc.z, colAcc[6]);
        colAcc[7] = fmaf(fq, cc.w, colAcc[7]);
      }
      if (wv == 3) {
        #pragma unroll
        for (int k = 0; k < 8; ++k) scr[(k << 6) + lane] = colAcc[k];
      }
    }
    asm volatile("s_waitcnt lgkmcnt(0)" ::: "memory");
    __builtin_amdgcn_s_barrier();        // barB
    __builtin_amdgcn_sched_barrier(0);
    if (wv == 2) {
      float* cp = ws + WS_COLPART + ((((size_t)rg << 6) + (size_t)b) << 13) +
                  (size_t)((jcur << 6) + lane) * 8;
      float s[8];
      #pragma unroll
      for (int k = 0; k < 8; ++k) s[k] = colAcc[k] + scr[(k << 6) + lane];
      float4 c0 = {s[0], s[1], s[2], s[3]};
      float4 c1 = {s[4], s[5], s[6], s[7]};
      *(float4*)cp = c0;
      *(float4*)(cp + 4) = c1;
    }
    if (wv >= 2) {
      #pragma unroll
      for (int k = 0; k < 8; ++k) colAcc[k] = 0.0f;
    }
    p ^= 1;
  }

  __syncthreads();
  if (wv == 1) {
    #pragma unroll
    for (int k = 0; k < 8; ++k) buf[0][(lane << 3) + k] = rowAcc[k];
  }
  __syncthreads();
  if (wv == 0) {
    float* rp = ws + WS_ROWAB + ((size_t)(b << 10) + i0 + lane) * 8;
    #pragma unroll
    for (int k = 0; k < 8; ++k) rowAcc[k] += buf[0][(lane << 3) + k];
    float4 c0 = {rowAcc[0], rowAcc[1], rowAcc[2], rowAcc[3]};
    float4 c1 = {rowAcc[4], rowAcc[5], rowAcc[6], rowAcc[7]};
    *(float4*)rp = c0;
    *(float4*)(rp + 4) = c1;
  }
}

// 7) final combine: grid (4,64), no barriers; sums 16 col partials;
//    read_modes recomputed per-thread from xi
__global__ __launch_bounds__(256) void k_final(const float* __restrict__ rw,
                                               const float* __restrict__ prec,
                                               const float* __restrict__ ws,
                                               float* __restrict__ out) {
  const int q = blockIdx.x, b = blockIdx.y, t = threadIdx.x;
  const float* xi = out + O_XI + b * XID;
  float md0[4], md1[4], md2[4];
  #pragma unroll
  for (int r = 0; r < 4; ++r) {
    float a = xi[459 + r * 3], bb = xi[459 + r * 3 + 1], c = xi[459 + r * 3 + 2];
    float m = fmaxf(a, fmaxf(bb, c));
    float ea = expf(a - m), eb = expf(bb - m), ec = expf(c - m);
    float s = 1.0f / (ea + eb + ec);
    md0[r] = ea * s; md1[r] = eb * s; md2[r] = ec * s;
  }
  float denom[4], ST[8];
  #pragma unroll
  for (int r = 0; r < 4; ++r)
    denom[r] = ws[WS_ERP + (b << 2) + r] + ws[WS_ERP + ((64 + b) << 2) + r] +
               ws[WS_ERP + ((128 + b) << 2) + r] + ws[WS_ERP + ((192 + b) << 2) + r];
  #pragma unroll
  for (int k = 0; k < 8; ++k)
    ST[k] = ws[WS_STP + (b << 3) + k] + ws[WS_STP + ((64 + b) << 3) + k] +
            ws[WS_STP + ((128 + b) << 3) + k] + ws[WS_STP + ((192 + b) << 3) + k];
  const int n = (q << 8) + t;
  const size_t bn = (size_t)(b << 10) + n;
  float4 er4 = *(const float4*)(ws + WS_ER + bn * 4);
  float cr[4] = {er4.x / denom[0], er4.y / denom[1], er4.z / denom[2], er4.w / denom[3]};
  float ca[8];
  #pragma unroll
  for (int k = 0; k < 8; ++k) ca[k] = 0.0f;
  #pragma unroll
  for (int rg = 0; rg < 16; ++rg) {
    const float* p = ws + WS_COLPART + ((((size_t)rg << 6) + (size_t)b) << 13) +
                     (size_t)n * 8;
    float4 a = *(const float4*)p;
    float4 c2 = *(const float4*)(p + 4);
    ca[0] += a.x; ca[1] += a.y; ca[2] += a.z; ca[3] += a.w;
    ca[4] += c2.x; ca[5] += c2.y; ca[6] += c2.z; ca[7] += c2.w;
  }
  const float* ra = ws + WS_ROWAB + bn * 8;
  float d = ws[WS_DIAG + bn];
  float w_ = ws[WS_WW + bn];
  float pn = prec[bn];
  float4 r4 = *(const float4*)(rw + bn * 4);
  float rv[4] = {r4.x, r4.y, r4.z, r4.w};
  float ow = 1.0f - w_;
  float res[4];
  #pragma unroll
  for (int r = 0; r < 4; ++r) {
    float A = ra[r], Ap = ra[4 + r], Bv = ca[r], Bp = ca[4 + r];
    float fwd = ow * (A - d * rv[r]) - (Ap - w_ * d * rv[r]) + w_ * (ST[r] - pn * rv[r]);
    float bwd = ow * (Bv - d * rv[r]) - (Bp - w_ * d * rv[r]) + pn * (ST[4 + r] - w_ * rv[r]);
    res[r] = md0[r] * bwd + md1[r] * cr[r] + md2[r] * fwd;
  }
  float4 o = {res[0], res[1], res[2], res[3]};
  *(float4*)(out + O_RW + bn * 4) = o;
}

extern "C" void kernel_launch(void* const* d_in, const int* in_sizes, int n_in,
                              void* d_out, int out_size, void* d_ws, size_t ws_size,
                              hipStream_t stream) {
  const float* x     = (const float*)d_in[0];
  const float* rw    = (const float*)d_in[1];
  const float* mem   = (const float*)d_in[2];
  const float* usage = (const float*)d_in[3];
  const float* wwp   = (const float*)d_in[4];
  const float* link  = (const float*)d_in[5];
  const float* prec  = (const float*)d_in[6];
  const float* W1    = (const float*)d_in[7];
  const float* b1    = (const float*)d_in[8];
  const float* Wo    = (const float*)d_in[9];
  const float* bo    = (const float*)d_in[10];
  const float* Wr    = (const float*)d_in[11];
  const float* br    = (const float*)d_in[12];
  const float* Wxi   = (const float*)d_in[13];
  const float* bxi   = (const float*)d_in[14];
  float* out = (float*)d_out;
  float* ws = (float*)d_ws;

  k_read_flat<<<dim3(4, 64), 1024, 0, stream>>>(mem, rw, ws);
  k_h<<<dim3(2, 64), 256, 0, stream>>>(x, W1, b1, ws);
  k_xiout<<<dim3(3, 64), 256, 0, stream>>>(Wxi, bxi, Wo, bo, Wr, br, ws, out);
  k_allocwc<<<dim3(8, 64), 256, 0, stream>>>(rw, usage, wwp, mem, link, ws, out);
  k_wcww_b<<<dim3(4, 64), 256, 0, stream>>>(mem, rw, prec, ws, out);
  k_link<<<dim3(16, 64), 256, 0, stream>>>(link, ws);
  k_final<<<dim3(4, 64), 256, 0, stream>>>(rw, prec, ws, out);
}

// Round 14
// 242.395 us; speedup vs baseline: 1.1072x; 1.0049x over previous
//
#include <hip/hip_runtime.h>

#define NB 64
#define NN 1024
#define WDIM 64
#define RR 4
#define HID 512
#define XID 471
#define EPSF 1e-6f

// ---- d_out offsets (floats) ----
#define O_OUT   0
#define O_XI    16384
#define O_RW    46528
#define O_MEM   308672
#define O_USAGE 4502976

// ---- ws offsets (floats) ----
#define WS_RFPART   0          // [4][64][256] read_flat partials
#define WS_H        65536      // [64][512]
#define WS_ALLOC    129024     // [64][1024]
#define WS_WW       194560     // [64][1024]
#define WS_V        260096     // [64][1024][8]
#define WS_DIAG     784896     // [64][1024]
#define WS_ROWAB    850432     // [64][1024][8]
#define WS_COLPART  1899008    // [16][64][1024][8] col partials (33.5 MB)
#define WS_EW       10287616   // [4][64]
#define WS_SIMWE    10287872   // [64][1024]
#define WS_ERP      10353408   // [4][64][4]
#define WS_ER       10354432   // [64][1024][4]
#define WS_STP      10616576   // [4][64][8]

__device__ __forceinline__ float sigmoidf_(float x) { return 1.0f / (1.0f + expf(-x)); }
__device__ __forceinline__ float oneplusf_(float x) {
  return 1.0f + ((x > 20.0f) ? x : log1pf(expf(x)));
}

typedef const __attribute__((address_space(1))) void gas_void;
typedef __attribute__((address_space(3))) void las_void;
__device__ __forceinline__ void gl16(const float* g, float* l) {
  __builtin_amdgcn_global_load_lds((gas_void*)g, (las_void*)l, 16, 0, 0);
}

// 1) read_flat partials
__global__ __launch_bounds__(1024) void k_read_flat(const float* __restrict__ mem,
                                                    const float* __restrict__ rw,
                                                    float* __restrict__ ws) {
  __shared__ float red[1024];
  const int q = blockIdx.x, b = blockIdx.y, t = threadIdx.x;
  const int rwi = t & 255;
  const int r = rwi >> 6, w = rwi & 63;
  const int ng = t >> 8;
  const int n0 = (q << 8) + (ng << 6);
  const float* M  = mem + ((size_t)(b << 10) + n0) * WDIM;
  const float* Rw = rw  + ((size_t)(b << 10) + n0) * RR;
  float a0 = 0.f, a1 = 0.f, a2 = 0.f, a3 = 0.f;
  for (int n = 0; n < 64; n += 4) {
    a0 += M[(n + 0) * WDIM + w] * Rw[(n + 0) * RR + r];
    a1 += M[(n + 1) * WDIM + w] * Rw[(n + 1) * RR + r];
    a2 += M[(n + 2) * WDIM + w] * Rw[(n + 2) * RR + r];
    a3 += M[(n + 3) * WDIM + w] * Rw[(n + 3) * RR + r];
  }
  red[t] = (a0 + a1) + (a2 + a3);
  __syncthreads();
  if (t < 256)
    ws[WS_RFPART + (((q << 6) + b) << 8) + t] =
        red[t] + red[t + 256] + red[t + 512] + red[t + 768];
}

// 2) h = relu([x, read_flat] @ W1 + b1), col-split grid (2,64); 4-acc ILP
__global__ __launch_bounds__(256) void k_h(const float* __restrict__ x,
                                           const float* __restrict__ W1,
                                           const float* __restrict__ b1,
                                           float* __restrict__ ws) {
  __shared__ float cat[768];
  const int ch = blockIdx.x, b = blockIdx.y, t = threadIdx.x;
  cat[t] = x[b * 512 + t];
  cat[256 + t] = x[b * 512 + 256 + t];
  {
    float s = 0.0f;
    #pragma unroll
    for (int q = 0; q < 4; ++q) s += ws[WS_RFPART + (((q << 6) + b) << 8) + t];
    cat[512 + t] = s;
  }
  __syncthreads();
  const int col = (ch << 8) + t;
  float a0 = 0.f, a1 = 0.f, a2 = 0.f, a3 = 0.f;
  #pragma unroll 4
  for (int k = 0; k < 768; k += 4) {
    a0 = fmaf(cat[k + 0], W1[(k + 0) * 512 + col], a0);
    a1 = fmaf(cat[k + 1], W1[(k + 1) * 512 + col], a1);
    a2 = fmaf(cat[k + 2], W1[(k + 2) * 512 + col], a2);
    a3 = fmaf(cat[k + 3], W1[(k + 3) * 512 + col], a3);
  }
  ws[WS_H + b * 512 + col] = fmaxf(b1[col] + (a0 + a1) + (a2 + a3), 0.0f);
}

// 3) xi (blocks 0,1) and output (block 2), grid (3,64); 4-acc ILP
__global__ __launch_bounds__(256) void k_xiout(const float* __restrict__ Wxi,
                                               const float* __restrict__ bxi,
                                               const float* __restrict__ Wo,
                                               const float* __restrict__ bo,
                                               const float* __restrict__ Wr,
                                               const float* __restrict__ br,
                                               const float* __restrict__ ws,
                                               float* __restrict__ out) {
  __shared__ float h[512];
  __shared__ float rf[256];
  const int m = blockIdx.x, b = blockIdx.y, t = threadIdx.x;
  h[t] = ws[WS_H + b * 512 + t];
  h[256 + t] = ws[WS_H + b * 512 + 256 + t];
  if (m == 2) {
    float s = 0.0f;
    #pragma unroll
    for (int q = 0; q < 4; ++q) s += ws[WS_RFPART + (((q << 6) + b) << 8) + t];
    rf[t] = s;
  }
  __syncthreads();
  if (m < 2) {
    const int col = (m << 8) + t;
    if (col < XID) {
      float a0 = 0.f, a1 = 0.f, a2 = 0.f, a3 = 0.f;
      #pragma unroll 4
      for (int j = 0; j < 512; j += 4) {
        a0 = fmaf(h[j + 0], Wxi[(j + 0) * XID + col], a0);
        a1 = fmaf(h[j + 1], Wxi[(j + 1) * XID + col], a1);
        a2 = fmaf(h[j + 2], Wxi[(j + 2) * XID + col], a2);
        a3 = fmaf(h[j + 3], Wxi[(j + 3) * XID + col], a3);
      }
      out[O_XI + b * XID + col] = bxi[col] + (a0 + a1) + (a2 + a3);
    }
  } else {
    float a0 = 0.f, a1 = 0.f, a2 = 0.f, a3 = 0.f;
    #pragma unroll 4
    for (int j = 0; j < 512; j += 4) {
      a0 = fmaf(h[j + 0], Wo[(j + 0) * 256 + t], a0);
      a1 = fmaf(h[j + 1], Wo[(j + 1) * 256 + t], a1);
      a2 = fmaf(h[j + 2], Wo[(j + 2) * 256 + t], a2);
      a3 = fmaf(h[j + 3], Wo[(j + 3) * 256 + t], a3);
    }
    #pragma unroll 4
    for (int j = 0; j < 256; j += 4) {
      a0 = fmaf(rf[j + 0], Wr[(j + 0) * 256 + t], a0);
      a1 = fmaf(rf[j + 1], Wr[(j + 1) * 256 + t], a1);
      a2 = fmaf(rf[j + 2], Wr[(j + 2) * 256 + t], a2);
      a3 = fmaf(rf[j + 3], Wr[(j + 3) * 256 + t], a3);
    }
    out[O_OUT + b * 256 + t] = bo[t] + br[t] + (a0 + a1) + (a2 + a3);
  }
}

// 4) fused: blocks 0-3 usage_new+allocation; blocks 4-7 write-content exp+diag
__global__ __launch_bounds__(256) void k_allocwc(const float* __restrict__ rw,
                                                 const float* __restrict__ usage,
                                                 const float* __restrict__ wwp,
                                                 const float* __restrict__ mem,
                                                 const float* __restrict__ link,
                                                 float* __restrict__ ws,
                                                 float* __restrict__ out) {
  __shared__ float ua[1024];
  __shared__ float la[1024];
  __shared__ float wkn[64];
  __shared__ float red[4];
  __shared__ float swstr;
  const int z = blockIdx.x, b = blockIdx.y, t = threadIdx.x;
  const float* xi = out + O_XI + b * XID;
  if (z < 4) {
    const int q = z;
    const float f0 = sigmoidf_(xi[453]), f1 = sigmoidf_(xi[454]);
    const float f2 = sigmoidf_(xi[455]), f3 = sigmoidf_(xi[456]);
    #pragma unroll
    for (int c = 0; c < 4; ++c) {
      const int n = (c << 8) + t;
      const int i = (b << 10) + n;
      const float4 r4 = *(const float4*)(rw + (size_t)i * 4);
      float ret = (1.0f - f0 * r4.x) * (1.0f - f1 * r4.y) *
                  (1.0f - f2 * r4.z) * (1.0f - f3 * r4.w);
      float u = usage[i], w = wwp[i];
      float un = (u + w - u * w) * ret;
      if (c == q) out[O_USAGE + i] = un;
      ua[n] = un;
      la[n] = logf(un);
    }
    __syncthreads();
    const int i = (q << 8) + t;
    const float ui = ua[i];
    float s0 = 0.f, s1 = 0.f, s2 = 0.f, s3 = 0.f;
    #pragma unroll 2
    for (int j = 0; j < 1024; j += 4) {
      float4 u4 = *(const float4*)(ua + j);
      float4 l4 = *(const float4*)(la + j);
      s0 += ((u4.x < ui) || (u4.x == ui && j + 0 < i)) ? l4.x : 0.0f;
      s1 += ((u4.y < ui) || (u4.y == ui && j + 1 < i)) ? l4.y : 0.0f;
      s2 += ((u4.z < ui) || (u4.z == ui && j + 2 < i)) ? l4.z : 0.0f;
      s3 += ((u4.w < ui) || (u4.w == ui && j + 3 < i)) ? l4.w : 0.0f;
    }
    ws[WS_ALLOC + (b << 10) + i] = (1.0f - ui) * expf((s0 + s1) + (s2 + s3));
  } else {
    const int q = z - 4;
    const int wv = t >> 6, lane = t & 63;
    if (t < 64) {
      float kv = xi[260 + t];
      float ss = kv * kv;
      #pragma unroll
      for (int s = 32; s; s >>= 1) ss += __shfl_xor(ss, s);
      wkn[t] = kv * rsqrtf(ss + EPSF);
    }
    if (t == 64) swstr = oneplusf_(xi[324]);
    __syncthreads();
    const int n = (q << 8) + t;
    const size_t bn = (size_t)(b << 10) + n;
    const float* Mrow = mem + bn * WDIM;
    float dot = 0.0f, ssq = 0.0f;
    #pragma unroll
    for (int w = 0; w < 64; w += 4) {
      float4 m4 = *(const float4*)(Mrow + w);
      float4 k4 = *(const float4*)(&wkn[w]);
      dot += m4.x * k4.x + m4.y * k4.y + m4.z * k4.z + m4.w * k4.w;
      ssq += m4.x * m4.x + m4.y * m4.y + m4.z * m4.z + m4.w * m4.w;
    }
    float e = expf(dot * rsqrtf(ssq + EPSF) * swstr);
    ws[WS_SIMWE + bn] = e;
    ws[WS_DIAG + bn] = link[bn * 1024 + n];
    float se = e;
    #pragma unroll
    for (int s = 32; s; s >>= 1) se += __shfl_xor(se, s);
    if (lane == 0) red[wv] = se;
    __syncthreads();
    if (t == 0) ws[WS_EW + (q << 6) + b] = red[0] + red[1] + red[2] + red[3];
  }
}

// 5) ww + V + ST partials + memory_new + fused read-content exp + partials
__global__ __launch_bounds__(256) void k_wcww_b(const float* __restrict__ mem,
                                                const float* __restrict__ rw,
                                                const float* __restrict__ prec,
                                                float* __restrict__ ws,
                                                float* __restrict__ out) {
  __shared__ float kn[256];
  __shared__ float shev[128];
  __shared__ float smisc[8];   // rstr[0..3], ag, wg
  __shared__ float red8[4][8];
  __shared__ float red4[4][4];
  const int q = blockIdx.x, b = blockIdx.y, t = threadIdx.x;
  const int wv = t >> 6, lane = t & 63;
  const float* xi = out + O_XI + b * XID;
  {
    float kv = xi[(wv << 6) + lane];
    float ss = kv * kv;
    #pragma unroll
    for (int s = 32; s; s >>= 1) ss += __shfl_xor(ss, s);
    kn[t] = kv * rsqrtf(ss + EPSF);
  }
  if (t < 64) shev[t] = sigmoidf_(xi[325 + t]);
  else if (t < 128) shev[t] = xi[389 + (t - 64)];
  else if (t < 132) smisc[t - 128] = oneplusf_(xi[256 + (t - 128)]);
  else if (t == 132) smisc[4] = sigmoidf_(xi[457]);
  else if (t == 133) smisc[5] = sigmoidf_(xi[458]);
  __syncthreads();
  const float denom = ws[WS_EW + b] + ws[WS_EW + 64 + b] +
                      ws[WS_EW + 128 + b] + ws[WS_EW + 192 + b];
  const int n = (q << 8) + t;
  const size_t bn = (size_t)(b << 10) + n;
  float wc = ws[WS_SIMWE + bn] / denom;
  float ag = smisc[4], wg = smisc[5];
  float ww = wg * (ag * ws[WS_ALLOC + bn] + (1.0f - ag) * wc);
  ws[WS_WW + bn] = ww;
  float4 r4 = *(const float4*)(rw + bn * 4);
  float* vp = ws + WS_V + bn * 8;
  float4 v0 = {r4.x, r4.y, r4.z, r4.w};
  float4 v1 = {ww * r4.x, ww * r4.y, ww * r4.z, ww * r4.w};
  *(float4*)vp = v0;
  *(float4*)(vp + 4) = v1;
  float p = prec[bn];
  float vals[8] = {p * r4.x, p * r4.y, p * r4.z, p * r4.w,
                   ww * r4.x, ww * r4.y, ww * r4.z, ww * r4.w};
  #pragma unroll
  for (int k = 0; k < 8; ++k) {
    float v = vals[k];
    #pragma unroll
    for (int s = 32; s; s >>= 1) v += __shfl_xor(v, s);
    vals[k] = v;
  }
  if (lane == 0) {
    #pragma unroll
    for (int k = 0; k < 8; ++k) red8[wv][k] = vals[k];
  }
  const float* Mrow = mem + bn * WDIM;
  float* Orow = out + O_MEM + bn * WDIM;
  float dr0 = 0.f, dr1 = 0.f, dr2 = 0.f, dr3 = 0.f, ssqn = 0.f;
  #pragma unroll
  for (int w4 = 0; w4 < 16; ++w4) {
    float4 m4 = *(const float4*)(Mrow + (w4 << 2));
    float4 e4 = *(const float4*)(&shev[w4 << 2]);
    float4 wv4 = *(const float4*)(&shev[64 + (w4 << 2)]);
    float4 o;
    o.x = m4.x * (1.0f - ww * e4.x) + ww * wv4.x;
    o.y = m4.y * (1.0f - ww * e4.y) + ww * wv4.y;
    o.z = m4.z * (1.0f - ww * e4.z) + ww * wv4.z;
    o.w = m4.w * (1.0f - ww * e4.w) + ww * wv4.w;
    *(float4*)(Orow + (w4 << 2)) = o;
    ssqn += o.x * o.x + o.y * o.y + o.z * o.z + o.w * o.w;
    float4 k0 = *(const float4*)(&kn[w4 << 2]);
    float4 k1 = *(const float4*)(&kn[64 + (w4 << 2)]);
    float4 k2 = *(const float4*)(&kn[128 + (w4 << 2)]);
    float4 k3 = *(const float4*)(&kn[192 + (w4 << 2)]);
    dr0 += o.x * k0.x + o.y * k0.y + o.z * k0.z + o.w * k0.w;
    dr1 += o.x * k1.x + o.y * k1.y + o.z * k1.z + o.w * k1.w;
    dr2 += o.x * k2.x + o.y * k2.y + o.z * k2.z + o.w * k2.w;
    dr3 += o.x * k3.x + o.y * k3.y + o.z * k3.z + o.w * k3.w;
  }
  float rs = rsqrtf(ssqn + EPSF);
  float er[4] = {expf(dr0 * rs * smisc[0]), expf(dr1 * rs * smisc[1]),
                 expf(dr2 * rs * smisc[2]), expf(dr3 * rs * smisc[3])};
  float4 er4 = {er[0], er[1], er[2], er[3]};
  *(float4*)(ws + WS_ER + bn * 4) = er4;
  #pragma unroll
  for (int r = 0; r < 4; ++r) {
    float v = er[r];
    #pragma unroll
    for (int s = 32; s; s >>= 1) v += __shfl_xor(v, s);
    er[r] = v;
  }
  if (lane == 0) {
    #pragma unroll
    for (int r = 0; r < 4; ++r) red4[wv][r] = er[r];
  }
  __syncthreads();
  if (t < 8)
    ws[WS_STP + (((q << 6) + b) << 3) + t] =
        red8[0][t] + red8[1][t] + red8[2][t] + red8[3][t];
  else if (t >= 64 && t < 68)
    ws[WS_ERP + (((q << 6) + b) << 2) + (t - 64)] =
        red4[0][t - 64] + red4[1][t - 64] + red4[2][t - 64] + red4[3][t - 64];
}

// 6) link pass v9: 64x128 tiles (512B-contiguous HBM segments per row),
//    8 column-phases, counted-vmcnt pipeline, conflict-balanced swizzle.
//    waves 0,1: row pass (lane=row, 64-col halves); waves 2,3: col pass
//    (each owns 64 full columns over all 64 rows -> direct colpart store).
__global__ __launch_bounds__(256, 2) void k_link(const float* __restrict__ link,
                                                 float* __restrict__ ws) {
  __shared__ float buf[2][8192];    // [2][64][128] swizzled link tiles (64KB)
  __shared__ float vtile[2][1024];  // [2][128][8]  (8KB)
  __shared__ float ublk[512];       // [64][8]      (2KB)   total 74KB
  const int rg = blockIdx.x, b = blockIdx.y;   // rg 0..15
  const int wv = threadIdx.x >> 6, lane = threadIdx.x & 63;
  const int i0 = rg << 6;
  const int rot = ((rg << 1) + b) & 7;
  const float* L = link + ((size_t)b << 20) + ((size_t)i0 << 10);
  const float* V = ws + WS_V + ((size_t)b << 13);

  // tile staging: wave wv covers 8 segments, each = 2 rows x 512B contiguous
  const float* gsrc[8];
  #pragma unroll
  for (int s = 0; s < 8; ++s) {
    const int row = (wv << 4) + (s << 1) + (lane >> 5);
    const int cb = (lane & 31) ^ (row & 31);
    gsrc[s] = L + (size_t)row * 1024 + (cb << 2);
  }

  float rowAcc[8], colAcc[8];
  #pragma unroll
  for (int k = 0; k < 8; ++k) { rowAcc[k] = 0.0f; colAcc[k] = 0.0f; }

  // prologue: phase `rot` tile + vtile + ublk, full drain once
  {
    const int c0 = rot << 7;
    #pragma unroll
    for (int s = 0; s < 8; ++s) gl16(gsrc[s] + c0, &buf[0][((wv << 3) + s) << 8]);
    if (wv < 2) {
      #pragma unroll
      for (int s = 0; s < 2; ++s)
        gl16(V + ((size_t)c0 << 3) + ((((wv << 1) + s) << 8) + (lane << 2)),
             &vtile[0][((wv << 1) + s) << 8]);
    } else {
      gl16(V + ((size_t)i0 << 3) + (((wv - 2) << 8) + (lane << 2)),
           &ublk[(wv - 2) << 8]);
    }
  }
  __syncthreads();

  int p = 0;
  #pragma unroll 1
  for (int jt = 0; jt < 8; ++jt) {
    const int jcur = ((jt + rot) & 7);
    // A) issue next-phase loads; counted wait keeps them in flight
    if (jt < 7) {
      const int jn = ((jt + 1 + rot) & 7) << 7;
      #pragma unroll
      for (int s = 0; s < 8; ++s)
        gl16(gsrc[s] + jn, &buf[p ^ 1][((wv << 3) + s) << 8]);
      if (wv < 2) {
        #pragma unroll
        for (int s = 0; s < 2; ++s)
          gl16(V + ((size_t)jn << 3) + ((((wv << 1) + s) << 8) + (lane << 2)),
               &vtile[p ^ 1][((wv << 1) + s) << 8]);
        asm volatile("s_waitcnt vmcnt(10)" ::: "memory");
      } else {
        asm volatile("s_waitcnt vmcnt(8)" ::: "memory");
      }
    } else {
      asm volatile("s_waitcnt vmcnt(0)" ::: "memory");
    }
    __builtin_amdgcn_sched_barrier(0);
    __builtin_amdgcn_s_barrier();        // barA: buf[p]/vtile[p] ready
    __builtin_amdgcn_sched_barrier(0);
    // B) compute on buf[p]
    const float* tb = &buf[p][0];
    if (wv < 2) {
      // row pass: lane = row (64), wv = 64-col half of the 128-col tile
      const float* base = tb + (lane << 7);
      const int rm = lane & 31;
      const float* vt = &vtile[p][0];
      #pragma unroll
      for (int jb = 0; jb < 16; ++jb) {
        const int jbb = (wv << 4) + jb;     // 16B block 0..31
        float4 f4 = *(const float4*)(base + ((jbb ^ rm) << 2));
        const float* vsb = vt + (jbb << 5);
        #pragma unroll
        for (int q = 0; q < 4; ++q) {
          float fq = (q == 0) ? f4.x : (q == 1) ? f4.y : (q == 2) ? f4.z : f4.w;
          float4 a = *(const float4*)(vsb + (q << 3));
          float4 c = *(const float4*)(vsb + (q << 3) + 4);
          rowAcc[0] = fmaf(fq, a.x, rowAcc[0]);
          rowAcc[1] = fmaf(fq, a.y, rowAcc[1]);
          rowAcc[2] = fmaf(fq, a.z, rowAcc[2]);
          rowAcc[3] = fmaf(fq, a.w, rowAcc[3]);
          rowAcc[4] = fmaf(fq, c.x, rowAcc[4]);
          rowAcc[5] = fmaf(fq, c.y, rowAcc[5]);
          rowAcc[6] = fmaf(fq, c.z, rowAcc[6]);
          rowAcc[7] = fmaf(fq, c.w, rowAcc[7]);
        }
      }
    } else {
      // col pass: lane = column within this wave's 64-col half, all 64 rows
      const int j = ((wv - 2) << 6) + lane;  // 0..127
      const int jb4 = j >> 2, jlo = j & 3;
      #pragma unroll 8
      for (int i = 0; i < 64; ++i) {
        float fq = tb[(i << 7) + (((jb4 ^ (i & 31)) << 2) | jlo)];
        const float* ur = &ublk[i << 3];     // wave-uniform -> broadcast
        float4 a = *(const float4*)ur;
        float4 cc = *(const float4*)(ur + 4);
        colAcc[0] = fmaf(fq, a.x, colAcc[0]);
        colAcc[1] = fmaf(fq, a.y, colAcc[1]);
        colAcc[2] = fmaf(fq, a.z, colAcc[2]);
        colAcc[3] = fmaf(fq, a.w, colAcc[3]);
        colAcc[4] = fmaf(fq, cc.x, colAcc[4]);
        colAcc[5] = fmaf(fq, cc.y, colAcc[5]);
        colAcc[6] = fmaf(fq, cc.z, colAcc[6]);
        colAcc[7] = fmaf(fq, cc.w, colAcc[7]);
      }
      // complete column sums for this phase -> direct store (no combine)
      float* cp = ws + WS_COLPART + ((((size_t)rg << 6) + (size_t)b) << 13) +
                  (size_t)((jcur << 7) + j) * 8;
      float4 c0 = {colAcc[0], colAcc[1], colAcc[2], colAcc[3]};
      float4 c1 = {colAcc[4], colAcc[5], colAcc[6], colAcc[7]};
      *(float4*)cp = c0;
      *(float4*)(cp + 4) = c1;
      #pragma unroll
      for (int k = 0; k < 8; ++k) colAcc[k] = 0.0f;
    }
    // C) barB: all waves done reading buf[p] before next iter overwrites it
    __builtin_amdgcn_s_barrier();
    __builtin_amdgcn_sched_barrier(0);
    p ^= 1;
  }

  // epilogue: combine row column-halves (wv0 + wv1)
  __syncthreads();
  if (wv == 1) {
    #pragma unroll
    for (int k = 0; k < 8; ++k) buf[0][(lane << 3) + k] = rowAcc[k];
  }
  __syncthreads();
  if (wv == 0) {
    float* rp = ws + WS_ROWAB + ((size_t)(b << 10) + i0 + lane) * 8;
    #pragma unroll
    for (int k = 0; k < 8; ++k) rowAcc[k] += buf[0][(lane << 3) + k];
    float4 c0 = {rowAcc[0], rowAcc[1], rowAcc[2], rowAcc[3]};
    float4 c1 = {rowAcc[4], rowAcc[5], rowAcc[6], rowAcc[7]};
    *(float4*)rp = c0;
    *(float4*)(rp + 4) = c1;
  }
}

// 7) final combine: grid (4,64), no barriers; sums 16 col partials;
//    read_modes recomputed per-thread from xi
__global__ __launch_bounds__(256) void k_final(const float* __restrict__ rw,
                                               const float* __restrict__ prec,
                                               const float* __restrict__ ws,
                                               float* __restrict__ out) {
  const int q = blockIdx.x, b = blockIdx.y, t = threadIdx.x;
  const float* xi = out + O_XI + b * XID;
  float md0[4], md1[4], md2[4];
  #pragma unroll
  for (int r = 0; r < 4; ++r) {
    float a = xi[459 + r * 3], bb = xi[459 + r * 3 + 1], c = xi[459 + r * 3 + 2];
    float m = fmaxf(a, fmaxf(bb, c));
    float ea = expf(a - m), eb = expf(bb - m), ec = expf(c - m);
    float s = 1.0f / (ea + eb + ec);
    md0[r] = ea * s; md1[r] = eb * s; md2[r] = ec * s;
  }
  float denom[4], ST[8];
  #pragma unroll
  for (int r = 0; r < 4; ++r)
    denom[r] = ws[WS_ERP + (b << 2) + r] + ws[WS_ERP + ((64 + b) << 2) + r] +
               ws[WS_ERP + ((128 + b) << 2) + r] + ws[WS_ERP + ((192 + b) << 2) + r];
  #pragma unroll
  for (int k = 0; k < 8; ++k)
    ST[k] = ws[WS_STP + (b << 3) + k] + ws[WS_STP + ((64 + b) << 3) + k] +
            ws[WS_STP + ((128 + b) << 3) + k] + ws[WS_STP + ((192 + b) << 3) + k];
  const int n = (q << 8) + t;
  const size_t bn = (size_t)(b << 10) + n;
  float4 er4 = *(const float4*)(ws + WS_ER + bn * 4);
  float cr[4] = {er4.x / denom[0], er4.y / denom[1], er4.z / denom[2], er4.w / denom[3]};
  float ca[8];
  #pragma unroll
  for (int k = 0; k < 8; ++k) ca[k] = 0.0f;
  #pragma unroll
  for (int rg = 0; rg < 16; ++rg) {
    const float* p = ws + WS_COLPART + ((((size_t)rg << 6) + (size_t)b) << 13) +
                     (size_t)n * 8;
    float4 a = *(const float4*)p;
    float4 c2 = *(const float4*)(p + 4);
    ca[0] += a.x; ca[1] += a.y; ca[2] += a.z; ca[3] += a.w;
    ca[4] += c2.x; ca[5] += c2.y; ca[6] += c2.z; ca[7] += c2.w;
  }
  const float* ra = ws + WS_ROWAB + bn * 8;
  float d = ws[WS_DIAG + bn];
  float w_ = ws[WS_WW + bn];
  float pn = prec[bn];
  float4 r4 = *(const float4*)(rw + bn * 4);
  float rv[4] = {r4.x, r4.y, r4.z, r4.w};
  float ow = 1.0f - w_;
  float res[4];
  #pragma unroll
  for (int r = 0; r < 4; ++r) {
    float A = ra[r], Ap = ra[4 + r], Bv = ca[r], Bp = ca[4 + r];
    float fwd = ow * (A - d * rv[r]) - (Ap - w_ * d * rv[r]) + w_ * (ST[r] - pn * rv[r]);
    float bwd = ow * (Bv - d * rv[r]) - (Bp - w_ * d * rv[r]) + pn * (ST[4 + r] - w_ * rv[r]);
    res[r] = md0[r] * bwd + md1[r] * cr[r] + md2[r] * fwd;
  }
  float4 o = {res[0], res[1], res[2], res[3]};
  *(float4*)(out + O_RW + bn * 4) = o;
}

extern "C" void kernel_launch(void* const* d_in, const int* in_sizes, int n_in,
                              void* d_out, int out_size, void* d_ws, size_t ws_size,
                              hipStream_t stream) {
  const float* x     = (const float*)d_in[0];
  const float* rw    = (const float*)d_in[1];
  const float* mem   = (const float*)d_in[2];
  const float* usage = (const float*)d_in[3];
  const float* wwp   = (const float*)d_in[4];
  const float* link  = (const float*)d_in[5];
  const float* prec  = (const float*)d_in[6];
  const float* W1    = (const float*)d_in[7];
  const float* b1    = (const float*)d_in[8];
  const float* Wo    = (const float*)d_in[9];
  const float* bo    = (const float*)d_in[10];
  const float* Wr    = (const float*)d_in[11];
  const float* br    = (const float*)d_in[12];
  const float* Wxi   = (const float*)d_in[13];
  const float* bxi   = (const float*)d_in[14];
  float* out = (float*)d_out;
  float* ws = (float*)d_ws;

  k_read_flat<<<dim3(4, 64), 1024, 0, stream>>>(mem, rw, ws);
  k_h<<<dim3(2, 64), 256, 0, stream>>>(x, W1, b1, ws);
  k_xiout<<<dim3(3, 64), 256, 0, stream>>>(Wxi, bxi, Wo, bo, Wr, br, ws, out);
  k_allocwc<<<dim3(8, 64), 256, 0, stream>>>(rw, usage, wwp, mem, link, ws, out);
  k_wcww_b<<<dim3(4, 64), 256, 0, stream>>>(mem, rw, prec, ws, out);
  k_link<<<dim3(16, 64), 256, 0, stream>>>(link, ws);
  k_final<<<dim3(4, 64), 256, 0, stream>>>(rw, prec, ws, out);
}

// Round 15
// 232.933 us; speedup vs baseline: 1.1522x; 1.0406x over previous
//
#include <hip/hip_runtime.h>

#define NB 64
#define NN 1024
#define WDIM 64
#define RR 4
#define HID 512
#define XID 471
#define EPSF 1e-6f

// ---- d_out offsets (floats) ----
#define O_OUT   0
#define O_XI    16384
#define O_RW    46528
#define O_MEM   308672
#define O_USAGE 4502976

// ---- ws offsets (floats) ----
#define WS_RFPART   0          // [4][64][256] read_flat partials
#define WS_H        65536      // [64][512]
#define WS_ALLOC    129024     // [64][1024]
#define WS_WW       194560     // [64][1024]
#define WS_V        260096     // [64][1024][8]
#define WS_DIAG     784896     // [64][1024]
#define WS_ROWAB    850432     // [64][1024][8]
#define WS_COLPART  1899008    // [16][64][1024][8] col partials (33.5 MB)
#define WS_EW       10287616   // [4][64]
#define WS_SIMWE    10287872   // [64][1024]
#define WS_ERP      10353408   // [4][64][4]
#define WS_ER       10354432   // [64][1024][4]
#define WS_STP      10616576   // [4][64][8]

__device__ __forceinline__ float sigmoidf_(float x) { return 1.0f / (1.0f + expf(-x)); }
__device__ __forceinline__ float oneplusf_(float x) {
  return 1.0f + ((x > 20.0f) ? x : log1pf(expf(x)));
}

typedef const __attribute__((address_space(1))) void gas_void;
typedef __attribute__((address_space(3))) void las_void;
__device__ __forceinline__ void gl16(const float* g, float* l) {
  __builtin_amdgcn_global_load_lds((gas_void*)g, (las_void*)l, 16, 0, 0);
}

// 1) read_flat partials
__global__ __launch_bounds__(1024) void k_read_flat(const float* __restrict__ mem,
                                                    const float* __restrict__ rw,
                                                    float* __restrict__ ws) {
  __shared__ float red[1024];
  const int q = blockIdx.x, b = blockIdx.y, t = threadIdx.x;
  const int rwi = t & 255;
  const int r = rwi >> 6, w = rwi & 63;
  const int ng = t >> 8;
  const int n0 = (q << 8) + (ng << 6);
  const float* M  = mem + ((size_t)(b << 10) + n0) * WDIM;
  const float* Rw = rw  + ((size_t)(b << 10) + n0) * RR;
  float a0 = 0.f, a1 = 0.f, a2 = 0.f, a3 = 0.f;
  for (int n = 0; n < 64; n += 4) {
    a0 += M[(n + 0) * WDIM + w] * Rw[(n + 0) * RR + r];
    a1 += M[(n + 1) * WDIM + w] * Rw[(n + 1) * RR + r];
    a2 += M[(n + 2) * WDIM + w] * Rw[(n + 2) * RR + r];
    a3 += M[(n + 3) * WDIM + w] * Rw[(n + 3) * RR + r];
  }
  red[t] = (a0 + a1) + (a2 + a3);
  __syncthreads();
  if (t < 256)
    ws[WS_RFPART + (((q << 6) + b) << 8) + t] =
        red[t] + red[t + 256] + red[t + 512] + red[t + 768];
}

// 2) h = relu([x, read_flat] @ W1 + b1), col-split grid (2,64); 4-acc ILP
__global__ __launch_bounds__(256) void k_h(const float* __restrict__ x,
                                           const float* __restrict__ W1,
                                           const float* __restrict__ b1,
                                           float* __restrict__ ws) {
  __shared__ float cat[768];
  const int ch = blockIdx.x, b = blockIdx.y, t = threadIdx.x;
  cat[t] = x[b * 512 + t];
  cat[256 + t] = x[b * 512 + 256 + t];
  {
    float s = 0.0f;
    #pragma unroll
    for (int q = 0; q < 4; ++q) s += ws[WS_RFPART + (((q << 6) + b) << 8) + t];
    cat[512 + t] = s;
  }
  __syncthreads();
  const int col = (ch << 8) + t;
  float a0 = 0.f, a1 = 0.f, a2 = 0.f, a3 = 0.f;
  #pragma unroll 4
  for (int k = 0; k < 768; k += 4) {
    a0 = fmaf(cat[k + 0], W1[(k + 0) * 512 + col], a0);
    a1 = fmaf(cat[k + 1], W1[(k + 1) * 512 + col], a1);
    a2 = fmaf(cat[k + 2], W1[(k + 2) * 512 + col], a2);
    a3 = fmaf(cat[k + 3], W1[(k + 3) * 512 + col], a3);
  }
  ws[WS_H + b * 512 + col] = fmaxf(b1[col] + (a0 + a1) + (a2 + a3), 0.0f);
}

// 3) xi (blocks 0,1) and output (block 2), grid (3,64); 4-acc ILP
__global__ __launch_bounds__(256) void k_xiout(const float* __restrict__ Wxi,
                                               const float* __restrict__ bxi,
                                               const float* __restrict__ Wo,
                                               const float* __restrict__ bo,
                                               const float* __restrict__ Wr,
                                               const float* __restrict__ br,
                                               const float* __restrict__ ws,
                                               float* __restrict__ out) {
  __shared__ float h[512];
  __shared__ float rf[256];
  const int m = blockIdx.x, b = blockIdx.y, t = threadIdx.x;
  h[t] = ws[WS_H + b * 512 + t];
  h[256 + t] = ws[WS_H + b * 512 + 256 + t];
  if (m == 2) {
    float s = 0.0f;
    #pragma unroll
    for (int q = 0; q < 4; ++q) s += ws[WS_RFPART + (((q << 6) + b) << 8) + t];
    rf[t] = s;
  }
  __syncthreads();
  if (m < 2) {
    const int col = (m << 8) + t;
    if (col < XID) {
      float a0 = 0.f, a1 = 0.f, a2 = 0.f, a3 = 0.f;
      #pragma unroll 4
      for (int j = 0; j < 512; j += 4) {
        a0 = fmaf(h[j + 0], Wxi[(j + 0) * XID + col], a0);
        a1 = fmaf(h[j + 1], Wxi[(j + 1) * XID + col], a1);
        a2 = fmaf(h[j + 2], Wxi[(j + 2) * XID + col], a2);
        a3 = fmaf(h[j + 3], Wxi[(j + 3) * XID + col], a3);
      }
      out[O_XI + b * XID + col] = bxi[col] + (a0 + a1) + (a2 + a3);
    }
  } else {
    float a0 = 0.f, a1 = 0.f, a2 = 0.f, a3 = 0.f;
    #pragma unroll 4
    for (int j = 0; j < 512; j += 4) {
      a0 = fmaf(h[j + 0], Wo[(j + 0) * 256 + t], a0);
      a1 = fmaf(h[j + 1], Wo[(j + 1) * 256 + t], a1);
      a2 = fmaf(h[j + 2], Wo[(j + 2) * 256 + t], a2);
      a3 = fmaf(h[j + 3], Wo[(j + 3) * 256 + t], a3);
    }
    #pragma unroll 4
    for (int j = 0; j < 256; j += 4) {
      a0 = fmaf(rf[j + 0], Wr[(j + 0) * 256 + t], a0);
      a1 = fmaf(rf[j + 1], Wr[(j + 1) * 256 + t], a1);
      a2 = fmaf(rf[j + 2], Wr[(j + 2) * 256 + t], a2);
      a3 = fmaf(rf[j + 3], Wr[(j + 3) * 256 + t], a3);
    }
    out[O_OUT + b * 256 + t] = bo[t] + br[t] + (a0 + a1) + (a2 + a3);
  }
}

// 4) fused: blocks 0-3 usage_new+allocation; blocks 4-7 write-content exp+diag
__global__ __launch_bounds__(256) void k_allocwc(const float* __restrict__ rw,
                                                 const float* __restrict__ usage,
                                                 const float* __restrict__ wwp,
                                                 const float* __restrict__ mem,
                                                 const float* __restrict__ link,
                                                 float* __restrict__ ws,
                                                 float* __restrict__ out) {
  __shared__ float ua[1024];
  __shared__ float la[1024];
  __shared__ float wkn[64];
  __shared__ float red[4];
  __shared__ float swstr;
  const int z = blockIdx.x, b = blockIdx.y, t = threadIdx.x;
  const float* xi = out + O_XI + b * XID;
  if (z < 4) {
    const int q = z;
    const float f0 = sigmoidf_(xi[453]), f1 = sigmoidf_(xi[454]);
    const float f2 = sigmoidf_(xi[455]), f3 = sigmoidf_(xi[456]);
    #pragma unroll
    for (int c = 0; c < 4; ++c) {
      const int n = (c << 8) + t;
      const int i = (b << 10) + n;
      const float4 r4 = *(const float4*)(rw + (size_t)i * 4);
      float ret = (1.0f - f0 * r4.x) * (1.0f - f1 * r4.y) *
                  (1.0f - f2 * r4.z) * (1.0f - f3 * r4.w);
      float u = usage[i], w = wwp[i];
      float un = (u + w - u * w) * ret;
      if (c == q) out[O_USAGE + i] = un;
      ua[n] = un;
      la[n] = logf(un);
    }
    __syncthreads();
    const int i = (q << 8) + t;
    const float ui = ua[i];
    float s0 = 0.f, s1 = 0.f, s2 = 0.f, s3 = 0.f;
    #pragma unroll 2
    for (int j = 0; j < 1024; j += 4) {
      float4 u4 = *(const float4*)(ua + j);
      float4 l4 = *(const float4*)(la + j);
      s0 += ((u4.x < ui) || (u4.x == ui && j + 0 < i)) ? l4.x : 0.0f;
      s1 += ((u4.y < ui) || (u4.y == ui && j + 1 < i)) ? l4.y : 0.0f;
      s2 += ((u4.z < ui) || (u4.z == ui && j + 2 < i)) ? l4.z : 0.0f;
      s3 += ((u4.w < ui) || (u4.w == ui && j + 3 < i)) ? l4.w : 0.0f;
    }
    ws[WS_ALLOC + (b << 10) + i] = (1.0f - ui) * expf((s0 + s1) + (s2 + s3));
  } else {
    const int q = z - 4;
    const int wv = t >> 6, lane = t & 63;
    if (t < 64) {
      float kv = xi[260 + t];
      float ss = kv * kv;
      #pragma unroll
      for (int s = 32; s; s >>= 1) ss += __shfl_xor(ss, s);
      wkn[t] = kv * rsqrtf(ss + EPSF);
    }
    if (t == 64) swstr = oneplusf_(xi[324]);
    __syncthreads();
    const int n = (q << 8) + t;
    const size_t bn = (size_t)(b << 10) + n;
    const float* Mrow = mem + bn * WDIM;
    float dot = 0.0f, ssq = 0.0f;
    #pragma unroll
    for (int w = 0; w < 64; w += 4) {
      float4 m4 = *(const float4*)(Mrow + w);
      float4 k4 = *(const float4*)(&wkn[w]);
      dot += m4.x * k4.x + m4.y * k4.y + m4.z * k4.z + m4.w * k4.w;
      ssq += m4.x * m4.x + m4.y * m4.y + m4.z * m4.z + m4.w * m4.w;
    }
    float e = expf(dot * rsqrtf(ssq + EPSF) * swstr);
    ws[WS_SIMWE + bn] = e;
    ws[WS_DIAG + bn] = link[bn * 1024 + n];
    float se = e;
    #pragma unroll
    for (int s = 32; s; s >>= 1) se += __shfl_xor(se, s);
    if (lane == 0) red[wv] = se;
    __syncthreads();
    if (t == 0) ws[WS_EW + (q << 6) + b] = red[0] + red[1] + red[2] + red[3];
  }
}

// 5) ww + V + ST partials + memory_new + fused read-content exp + partials
__global__ __launch_bounds__(256) void k_wcww_b(const float* __restrict__ mem,
                                                const float* __restrict__ rw,
                                                const float* __restrict__ prec,
                                                float* __restrict__ ws,
                                                float* __restrict__ out) {
  __shared__ float kn[256];
  __shared__ float shev[128];
  __shared__ float smisc[8];   // rstr[0..3], ag, wg
  __shared__ float red8[4][8];
  __shared__ float red4[4][4];
  const int q = blockIdx.x, b = blockIdx.y, t = threadIdx.x;
  const int wv = t >> 6, lane = t & 63;
  const float* xi = out + O_XI + b * XID;
  {
    float kv = xi[(wv << 6) + lane];
    float ss = kv * kv;
    #pragma unroll
    for (int s = 32; s; s >>= 1) ss += __shfl_xor(ss, s);
    kn[t] = kv * rsqrtf(ss + EPSF);
  }
  if (t < 64) shev[t] = sigmoidf_(xi[325 + t]);
  else if (t < 128) shev[t] = xi[389 + (t - 64)];
  else if (t < 132) smisc[t - 128] = oneplusf_(xi[256 + (t - 128)]);
  else if (t == 132) smisc[4] = sigmoidf_(xi[457]);
  else if (t == 133) smisc[5] = sigmoidf_(xi[458]);
  __syncthreads();
  const float denom = ws[WS_EW + b] + ws[WS_EW + 64 + b] +
                      ws[WS_EW + 128 + b] + ws[WS_EW + 192 + b];
  const int n = (q << 8) + t;
  const size_t bn = (size_t)(b << 10) + n;
  float wc = ws[WS_SIMWE + bn] / denom;
  float ag = smisc[4], wg = smisc[5];
  float ww = wg * (ag * ws[WS_ALLOC + bn] + (1.0f - ag) * wc);
  ws[WS_WW + bn] = ww;
  float4 r4 = *(const float4*)(rw + bn * 4);
  float* vp = ws + WS_V + bn * 8;
  float4 v0 = {r4.x, r4.y, r4.z, r4.w};
  float4 v1 = {ww * r4.x, ww * r4.y, ww * r4.z, ww * r4.w};
  *(float4*)vp = v0;
  *(float4*)(vp + 4) = v1;
  float p = prec[bn];
  float vals[8] = {p * r4.x, p * r4.y, p * r4.z, p * r4.w,
                   ww * r4.x, ww * r4.y, ww * r4.z, ww * r4.w};
  #pragma unroll
  for (int k = 0; k < 8; ++k) {
    float v = vals[k];
    #pragma unroll
    for (int s = 32; s; s >>= 1) v += __shfl_xor(v, s);
    vals[k] = v;
  }
  if (lane == 0) {
    #pragma unroll
    for (int k = 0; k < 8; ++k) red8[wv][k] = vals[k];
  }
  const float* Mrow = mem + bn * WDIM;
  float* Orow = out + O_MEM + bn * WDIM;
  float dr0 = 0.f, dr1 = 0.f, dr2 = 0.f, dr3 = 0.f, ssqn = 0.f;
  #pragma unroll
  for (int w4 = 0; w4 < 16; ++w4) {
    float4 m4 = *(const float4*)(Mrow + (w4 << 2));
    float4 e4 = *(const float4*)(&shev[w4 << 2]);
    float4 wv4 = *(const float4*)(&shev[64 + (w4 << 2)]);
    float4 o;
    o.x = m4.x * (1.0f - ww * e4.x) + ww * wv4.x;
    o.y = m4.y * (1.0f - ww * e4.y) + ww * wv4.y;
    o.z = m4.z * (1.0f - ww * e4.z) + ww * wv4.z;
    o.w = m4.w * (1.0f - ww * e4.w) + ww * wv4.w;
    *(float4*)(Orow + (w4 << 2)) = o;
    ssqn += o.x * o.x + o.y * o.y + o.z * o.z + o.w * o.w;
    float4 k0 = *(const float4*)(&kn[w4 << 2]);
    float4 k1 = *(const float4*)(&kn[64 + (w4 << 2)]);
    float4 k2 = *(const float4*)(&kn[128 + (w4 << 2)]);
    float4 k3 = *(const float4*)(&kn[192 + (w4 << 2)]);
    dr0 += o.x * k0.x + o.y * k0.y + o.z * k0.z + o.w * k0.w;
    dr1 += o.x * k1.x + o.y * k1.y + o.z * k1.z + o.w * k1.w;
    dr2 += o.x * k2.x + o.y * k2.y + o.z * k2.z + o.w * k2.w;
    dr3 += o.x * k3.x + o.y * k3.y + o.z * k3.z + o.w * k3.w;
  }
  float rs = rsqrtf(ssqn + EPSF);
  float er[4] = {expf(dr0 * rs * smisc[0]), expf(dr1 * rs * smisc[1]),
                 expf(dr2 * rs * smisc[2]), expf(dr3 * rs * smisc[3])};
  float4 er4 = {er[0], er[1], er[2], er[3]};
  *(float4*)(ws + WS_ER + bn * 4) = er4;
  #pragma unroll
  for (int r = 0; r < 4; ++r) {
    float v = er[r];
    #pragma unroll
    for (int s = 32; s; s >>= 1) v += __shfl_xor(v, s);
    er[r] = v;
  }
  if (lane == 0) {
    #pragma unroll
    for (int r = 0; r < 4; ++r) red4[wv][r] = er[r];
  }
  __syncthreads();
  if (t < 8)
    ws[WS_STP + (((q << 6) + b) << 3) + t] =
        red8[0][t] + red8[1][t] + red8[2][t] + red8[3][t];
  else if (t >= 64 && t < 68)
    ws[WS_ERP + (((q << 6) + b) << 2) + (t - 64)] =
        red4[0][t - 64] + red4[1][t - 64] + red4[2][t - 64] + red4[3][t - 64];
}

// 6) link pass v11: DEPTH-2 prefetch pipeline — 3 LDS buffers, loads for
//    phase jt+2 issued while computing jt; phase time decouples from HBM
//    round-trip. Otherwise identical to the proven r11 v7 structure
//    (64x64 tiles, conflict-free col pass, 256 thr, grid (16,64)).
__global__ __launch_bounds__(256, 2) void k_link(const float* __restrict__ link,
                                                 float* __restrict__ ws) {
  __shared__ float buf[3][4096];    // [3][64][64] swizzled link tiles (48KB)
  __shared__ float vtile[3][512];   // [3][64][8]  (6KB)
  __shared__ float ublk[512];       // [64][8]     (2KB)
  __shared__ float scr[512];        // [8][64]     (2KB)   total 58KB
  const int rg = blockIdx.x, b = blockIdx.y;   // rg 0..15
  const int wv = threadIdx.x >> 6, lane = threadIdx.x & 63;
  const int i0 = rg << 6;
  const int rot = ((rg << 1) + b) & 15;
  const float* L = link + ((size_t)b << 20) + ((size_t)i0 << 10);
  const float* V = ws + WS_V + ((size_t)b << 13);

  const float* gsrc[4];
  #pragma unroll
  for (int s = 0; s < 4; ++s) {
    const int qq = (wv << 2) + s;
    const int row = (qq << 2) + (lane >> 4);
    const int cb = (lane & 15) ^ (row & 15);
    gsrc[s] = L + (size_t)row * 1024 + (cb << 2);
  }

  float rowAcc[8], colAcc[8];
  #pragma unroll
  for (int k = 0; k < 8; ++k) { rowAcc[k] = 0.0f; colAcc[k] = 0.0f; }

  // prologue: ublk first (oldest), then phases rot, rot+1 into buf[0], buf[1]
  if (wv >= 2)
    gl16(V + ((size_t)(i0 + ((wv - 2) << 5)) << 3) + (lane << 2),
         &ublk[(wv - 2) << 8]);
  #pragma unroll
  for (int ph = 0; ph < 2; ++ph) {
    const int c0 = ((ph + rot) & 15) << 6;
    #pragma unroll
    for (int s = 0; s < 4; ++s) gl16(gsrc[s] + c0, &buf[ph][((wv << 2) + s) << 8]);
    if (wv < 2)
      gl16(V + ((size_t)c0 << 3) + (wv << 8) + (lane << 2), &vtile[ph][wv << 8]);
  }

  int p = 0;
  #pragma unroll 1
  for (int jt = 0; jt < 16; ++jt) {
    const int jcur = ((jt + rot) & 15);
    // A) issue phase jt+2; counted wait leaves jt+1, jt+2 in flight
    if (jt < 14) {
      int pn = p + 2; if (pn >= 3) pn -= 3;
      const int jn = ((jt + 2 + rot) & 15) << 6;
      #pragma unroll
      for (int s = 0; s < 4; ++s)
        gl16(gsrc[s] + jn, &buf[pn][((wv << 2) + s) << 8]);
      if (wv < 2) {
        gl16(V + ((size_t)jn << 3) + (wv << 8) + (lane << 2), &vtile[pn][wv << 8]);
        asm volatile("s_waitcnt vmcnt(10)" ::: "memory");
      } else {
        if (jt == 0)      asm volatile("s_waitcnt vmcnt(8)"  ::: "memory");
        else if (jt == 1) asm volatile("s_waitcnt vmcnt(10)" ::: "memory");
        else              asm volatile("s_waitcnt vmcnt(12)" ::: "memory");
      }
    } else if (jt == 14) {
      if (wv < 2) asm volatile("s_waitcnt vmcnt(5)" ::: "memory");
      else        asm volatile("s_waitcnt vmcnt(8)" ::: "memory");
    } else {
      if (wv < 2) asm volatile("s_waitcnt vmcnt(0)" ::: "memory");
      else        asm volatile("s_waitcnt vmcnt(4)" ::: "memory");
    }
    __builtin_amdgcn_sched_barrier(0);
    __builtin_amdgcn_s_barrier();        // barA: buf[p]/vtile[p] ready
    __builtin_amdgcn_sched_barrier(0);
    // B) compute on buf[p]
    const float* tb = &buf[p][0];
    if (wv < 2) {
      const float* base = tb + (lane << 6);
      const int rm = lane & 15;
      const float* vt = &vtile[p][0];
      #pragma unroll
      for (int jb8 = 0; jb8 < 8; ++jb8) {
        const int jb = (wv << 3) + jb8;
        float4 f4 = *(const float4*)(base + ((jb ^ rm) << 2));
        const float* vsb = vt + (jb << 5);
        #pragma unroll
        for (int q = 0; q < 4; ++q) {
          float fq = (q == 0) ? f4.x : (q == 1) ? f4.y : (q == 2) ? f4.z : f4.w;
          float4 a = *(const float4*)(vsb + (q << 3));
          float4 c = *(const float4*)(vsb + (q << 3) + 4);
          rowAcc[0] = fmaf(fq, a.x, rowAcc[0]);
          rowAcc[1] = fmaf(fq, a.y, rowAcc[1]);
          rowAcc[2] = fmaf(fq, a.z, rowAcc[2]);
          rowAcc[3] = fmaf(fq, a.w, rowAcc[3]);
          rowAcc[4] = fmaf(fq, c.x, rowAcc[4]);
          rowAcc[5] = fmaf(fq, c.y, rowAcc[5]);
          rowAcc[6] = fmaf(fq, c.z, rowAcc[6]);
          rowAcc[7] = fmaf(fq, c.w, rowAcc[7]);
        }
      }
    } else {
      const int iq = wv - 2;
      #pragma unroll 8
      for (int ii = 0; ii < 32; ++ii) {
        const int i = (iq << 5) + ii;
        float fq = tb[(i << 6) + ((((lane >> 2) ^ (i & 15)) << 2) | (lane & 3))];
        const float* ur = &ublk[i << 3];   // wave-uniform -> broadcast
        float4 a = *(const float4*)ur;
        float4 cc = *(const float4*)(ur + 4);
        colAcc[0] = fmaf(fq, a.x, colAcc[0]);
        colAcc[1] = fmaf(fq, a.y, colAcc[1]);
        colAcc[2] = fmaf(fq, a.z, colAcc[2]);
        colAcc[3] = fmaf(fq, a.w, colAcc[3]);
        colAcc[4] = fmaf(fq, cc.x, colAcc[4]);
        colAcc[5] = fmaf(fq, cc.y, colAcc[5]);
        colAcc[6] = fmaf(fq, cc.z, colAcc[6]);
        colAcc[7] = fmaf(fq, cc.w, colAcc[7]);
      }
      if (wv == 3) {
        #pragma unroll
        for (int k = 0; k < 8; ++k) scr[(k << 6) + lane] = colAcc[k];
      }
    }
    asm volatile("s_waitcnt lgkmcnt(0)" ::: "memory");
    __builtin_amdgcn_s_barrier();        // barB: reads of buf[p] done, scr visible
    __builtin_amdgcn_sched_barrier(0);
    if (wv == 2) {
      float* cp = ws + WS_COLPART + ((((size_t)rg << 6) + (size_t)b) << 13) +
                  (size_t)((jcur << 6) + lane) * 8;
      float s[8];
      #pragma unroll
      for (int k = 0; k < 8; ++k) s[k] = colAcc[k] + scr[(k << 6) + lane];
      float4 c0 = {s[0], s[1], s[2], s[3]};
      float4 c1 = {s[4], s[5], s[6], s[7]};
      *(float4*)cp = c0;
      *(float4*)(cp + 4) = c1;
    }
    if (wv >= 2) {
      #pragma unroll
      for (int k = 0; k < 8; ++k) colAcc[k] = 0.0f;
    }
    p = (p == 2) ? 0 : p + 1;
  }

  // epilogue: combine row column-halves (wv0 + wv1)
  __syncthreads();
  if (wv == 1) {
    #pragma unroll
    for (int k = 0; k < 8; ++k) buf[0][(lane << 3) + k] = rowAcc[k];
  }
  __syncthreads();
  if (wv == 0) {
    float* rp = ws + WS_ROWAB + ((size_t)(b << 10) + i0 + lane) * 8;
    #pragma unroll
    for (int k = 0; k < 8; ++k) rowAcc[k] += buf[0][(lane << 3) + k];
    float4 c0 = {rowAcc[0], rowAcc[1], rowAcc[2], rowAcc[3]};
    float4 c1 = {rowAcc[4], rowAcc[5], rowAcc[6], rowAcc[7]};
    *(float4*)rp = c0;
    *(float4*)(rp + 4) = c1;
  }
}

// 7) final combine: grid (4,64), no barriers; sums 16 col partials;
//    read_modes recomputed per-thread from xi
__global__ __launch_bounds__(256) void k_final(const float* __restrict__ rw,
                                               const float* __restrict__ prec,
                                               const float* __restrict__ ws,
                                               float* __restrict__ out) {
  const int q = blockIdx.x, b = blockIdx.y, t = threadIdx.x;
  const float* xi = out + O_XI + b * XID;
  float md0[4], md1[4], md2[4];
  #pragma unroll
  for (int r = 0; r < 4; ++r) {
    float a = xi[459 + r * 3], bb = xi[459 + r * 3 + 1], c = xi[459 + r * 3 + 2];
    float m = fmaxf(a, fmaxf(bb, c));
    float ea = expf(a - m), eb = expf(bb - m), ec = expf(c - m);
    float s = 1.0f / (ea + eb + ec);
    md0[r] = ea * s; md1[r] = eb * s; md2[r] = ec * s;
  }
  float denom[4], ST[8];
  #pragma unroll
  for (int r = 0; r < 4; ++r)
    denom[r] = ws[WS_ERP + (b << 2) + r] + ws[WS_ERP + ((64 + b) << 2) + r] +
               ws[WS_ERP + ((128 + b) << 2) + r] + ws[WS_ERP + ((192 + b) << 2) + r];
  #pragma unroll
  for (int k = 0; k < 8; ++k)
    ST[k] = ws[WS_STP + (b << 3) + k] + ws[WS_STP + ((64 + b) << 3) + k] +
            ws[WS_STP + ((128 + b) << 3) + k] + ws[WS_STP + ((192 + b) << 3) + k];
  const int n = (q << 8) + t;
  const size_t bn = (size_t)(b << 10) + n;
  float4 er4 = *(const float4*)(ws + WS_ER + bn * 4);
  float cr[4] = {er4.x / denom[0], er4.y / denom[1], er4.z / denom[2], er4.w / denom[3]};
  float ca[8];
  #pragma unroll
  for (int k = 0; k < 8; ++k) ca[k] = 0.0f;
  #pragma unroll
  for (int rg = 0; rg < 16; ++rg) {
    const float* p = ws + WS_COLPART + ((((size_t)rg << 6) + (size_t)b) << 13) +
                     (size_t)n * 8;
    float4 a = *(const float4*)p;
    float4 c2 = *(const float4*)(p + 4);
    ca[0] += a.x; ca[1] += a.y; ca[2] += a.z; ca[3] += a.w;
    ca[4] += c2.x; ca[5] += c2.y; ca[6] += c2.z; ca[7] += c2.w;
  }
  const float* ra = ws + WS_ROWAB + bn * 8;
  float d = ws[WS_DIAG + bn];
  float w_ = ws[WS_WW + bn];
  float pn = prec[bn];
  float4 r4 = *(const float4*)(rw + bn * 4);
  float rv[4] = {r4.x, r4.y, r4.z, r4.w};
  float ow = 1.0f - w_;
  float res[4];
  #pragma unroll
  for (int r = 0; r < 4; ++r) {
    float A = ra[r], Ap = ra[4 + r], Bv = ca[r], Bp = ca[4 + r];
    float fwd = ow * (A - d * rv[r]) - (Ap - w_ * d * rv[r]) + w_ * (ST[r] - pn * rv[r]);
    float bwd = ow * (Bv - d * rv[r]) - (Bp - w_ * d * rv[r]) + pn * (ST[4 + r] - w_ * rv[r]);
    res[r] = md0[r] * bwd + md1[r] * cr[r] + md2[r] * fwd;
  }
  float4 o = {res[0], res[1], res[2], res[3]};
  *(float4*)(out + O_RW + bn * 4) = o;
}

extern "C" void kernel_launch(void* const* d_in, const int* in_sizes, int n_in,
                              void* d_out, int out_size, void* d_ws, size_t ws_size,
                              hipStream_t stream) {
  const float* x     = (const float*)d_in[0];
  const float* rw    = (const float*)d_in[1];
  const float* mem   = (const float*)d_in[2];
  const float* usage = (const float*)d_in[3];
  const float* wwp   = (const float*)d_in[4];
  const float* link  = (const float*)d_in[5];
  const float* prec  = (const float*)d_in[6];
  const float* W1    = (const float*)d_in[7];
  const float* b1    = (const float*)d_in[8];
  const float* Wo    = (const float*)d_in[9];
  const float* bo    = (const float*)d_in[10];
  const float* Wr    = (const float*)d_in[11];
  const float* br    = (const float*)d_in[12];
  const float* Wxi   = (const float*)d_in[13];
  const float* bxi   = (const float*)d_in[14];
  float* out = (float*)d_out;
  float* ws = (float*)d_ws;

  k_read_flat<<<dim3(4, 64), 1024, 0, stream>>>(mem, rw, ws);
  k_h<<<dim3(2, 64), 256, 0, stream>>>(x, W1, b1, ws);
  k_xiout<<<dim3(3, 64), 256, 0, stream>>>(Wxi, bxi, Wo, bo, Wr, br, ws, out);
  k_allocwc<<<dim3(8, 64), 256, 0, stream>>>(rw, usage, wwp, mem, link, ws, out);
  k_wcww_b<<<dim3(4, 64), 256, 0, stream>>>(mem, rw, prec, ws, out);
  k_link<<<dim3(16, 64), 256, 0, stream>>>(link, ws);
  k_final<<<dim3(4, 64), 256, 0, stream>>>(rw, prec, ws, out);
}